// Round 12
// baseline (2640.956 us; speedup 1.0000x reference)
//
#include <hip/hip_runtime.h>

#define NATOM 10000
#define EG    120000
#define TT    600000

#define INV_SQRT2f 0.7071067811865476f

typedef unsigned short bf16t;
typedef __attribute__((ext_vector_type(8))) short s16x8;
typedef __attribute__((ext_vector_type(8))) unsigned short u16x8;
typedef __attribute__((ext_vector_type(4))) float f32x4;

__device__ __forceinline__ float ssilu(float x) {
    return x * (1.0f / (1.0f + __expf(-x))) * (1.0f / 0.6f);
}
__device__ __forceinline__ float bf2f(unsigned short u) {
    return __uint_as_float(((unsigned)u) << 16);
}
__device__ __forceinline__ unsigned short f2bf(float f) {
    unsigned b = __float_as_uint(f);
    unsigned r = (b + 0x7FFF + ((b >> 16) & 1)) >> 16;  // RNE
    return (unsigned short)r;
}
__device__ __forceinline__ u16x8 cvt8(const float4 va, const float4 vb) {
    u16x8 r{};
    r[0] = f2bf(va.x); r[1] = f2bf(va.y); r[2] = f2bf(va.z); r[3] = f2bf(va.w);
    r[4] = f2bf(vb.x); r[5] = f2bf(vb.y); r[6] = f2bf(vb.z); r[7] = f2bf(vb.w);
    return r;
}

// ---------------------------------------------------------------------------
__global__ __launch_bounds__(256) void k_fill(float* __restrict__ o, int n, float v) {
    int i = blockIdx.x * 256 + threadIdx.x;
    if (i < n) o[i] = v;
}

// ---------------------------------------------------------------------------
// sort infrastructure (built once; indices are launch-constant)
// ---------------------------------------------------------------------------
__global__ __launch_bounds__(256) void k_hist(
    const int* __restrict__ idx, int* __restrict__ cnt, int n)
{
    int i = blockIdx.x * 256 + threadIdx.x;
    if (i < n) atomicAdd(&cnt[idx[i]], 1);
}

__global__ __launch_bounds__(1024) void k_scan(
    const int* __restrict__ cnt, int* __restrict__ off, int n)
{
    __shared__ int wsum[16];
    __shared__ int carrySh;
    if (threadIdx.x == 0) carrySh = 0;
    __syncthreads();
    const int lane = threadIdx.x & 63, wid = threadIdx.x >> 6;
    for (int base = 0; base < n; base += 8192) {
        int v[8]; int s = 0;
        int i0 = base + threadIdx.x * 8;
#pragma unroll
        for (int j = 0; j < 8; j++) { int i = i0 + j; v[j] = (i < n) ? cnt[i] : 0; s += v[j]; }
        int sc = s;
#pragma unroll
        for (int d = 1; d < 64; d <<= 1) { int t = __shfl_up(sc, d); if (lane >= d) sc += t; }
        if (lane == 63) wsum[wid] = sc;
        __syncthreads();
        int wbase = 0;
        for (int w = 0; w < 16; w++) wbase += (w < wid) ? wsum[w] : 0;
        int carry = carrySh;
        int excl = carry + wbase + (sc - s);
#pragma unroll
        for (int j = 0; j < 8; j++) { int i = i0 + j; if (i < n) off[i] = excl; excl += v[j]; }
        __syncthreads();
        if (threadIdx.x == 1023) carrySh = carry + wbase + sc;
        __syncthreads();
    }
    if (threadIdx.x == 0) off[n] = carrySh;
}

__global__ __launch_bounds__(256) void k_rank_trip(
    const int* __restrict__ id3_ca, const int* __restrict__ id3_ba,
    const int* __restrict__ off, int* __restrict__ cnt2,
    int* __restrict__ rank, int* __restrict__ ba_s, int* __restrict__ ca_s, int n)
{
    int t = blockIdx.x * 256 + threadIdx.x;
    if (t >= n) return;
    int ca = id3_ca[t];
    int p = off[ca] + atomicAdd(&cnt2[ca], 1);
    rank[t] = p;
    ba_s[p] = id3_ba[t];
    ca_s[p] = ca;
}

__global__ __launch_bounds__(256) void k_rank_edge(
    const int* __restrict__ idx, const int* __restrict__ off,
    int* __restrict__ cnt2, int* __restrict__ lst, int n)
{
    int i = blockIdx.x * 256 + threadIdx.x;
    if (i >= n) return;
    int a = idx[i];
    int p = off[a] + atomicAdd(&cnt2[a], 1);
    lst[p] = i;
}

// segment sum: out[n][256] (bf16) = sum of X rows (bf16) with target n (CSR)
__global__ __launch_bounds__(256) void k_segsum(
    const bf16t* __restrict__ X, const int* __restrict__ off,
    const int* __restrict__ lst, bf16t* __restrict__ out)
{
    int n = blockIdx.x, j = threadIdx.x;
    int b = off[n], e = off[n + 1];
    float s = 0.f;
    for (int k = b; k < e; k++) s += bf2f(X[(size_t)lst[k] * 256 + j]);
    out[(size_t)n * 256 + j] = f2bf(s);
}

// ---------------------------------------------------------------------------
// batched weight transpose: mode 0 -> BT[n][KP], mode 1 -> bilinear interleave
// ---------------------------------------------------------------------------
struct WtE { const float* src; unsigned dstOff; int K, KP, N, mode; };
struct WtBatch { WtE e[12]; int n; };

__global__ __launch_bounds__(256) void k_wt_batch(WtBatch b, bf16t* __restrict__ base)
{
    for (int i = 0; i < b.n; i++) {
        const WtE E = b.e[i];
        int total = (E.mode == 0) ? E.N * E.KP : 16 * 64 * 64;
        for (int idx = blockIdx.x * 256 + threadIdx.x; idx < total; idx += gridDim.x * 256) {
            bf16t v;
            if (E.mode == 0) {
                int n = idx / E.KP, k = idx - n * E.KP;
                v = (k < E.K) ? f2bf(E.src[(size_t)k * E.N + n]) : (bf16t)0;
            } else {
                int e8 = idx & 7, o = (idx >> 3) & 63, ch = (idx >> 9) & 7, ii = idx >> 12;
                v = f2bf(E.src[((size_t)(ch * 8 + e8) * 16 + ii) * 64 + o]);
            }
            base[E.dstOff + idx] = v;
        }
    }
}

// batched 16x16 @ 16x256 weight combines
struct WcE { const float* Wa; const float* Wb; };
struct WcBatch { WcE e[7]; };

__global__ __launch_bounds__(256) void k_wcomb_batch(WcBatch b, float* __restrict__ wcb)
{
    __shared__ float sA[256];
    int c = blockIdx.x, j = threadIdx.x;
    sA[j] = b.e[c].Wa[j];
    __syncthreads();
    const float* Wb = b.e[c].Wb;
    float* dst = wcb + (size_t)c * 4096;
#pragma unroll 4
    for (int r = 0; r < 16; r++) {
        float acc = 0.f;
#pragma unroll
        for (int k = 0; k < 16; k++) acc = fmaf(sA[r * 16 + k], Wb[k * 256 + j], acc);
        dst[r * 256 + j] = acc;
    }
}

// ---------------------------------------------------------------------------
// rbf basis + rbf_W1 (cbf down-projection)
// ---------------------------------------------------------------------------
__global__ __launch_bounds__(256) void k_rbf(
    const float* __restrict__ D, const float* __restrict__ Wc,
    bf16t* __restrict__ rbf, float* __restrict__ rbfW1)
{
    __shared__ float sW[1792];
    for (int i = threadIdx.x; i < 1792; i += 256) sW[i] = Wc[i];
    __syncthreads();
    int e = blockIdx.x * 256 + threadIdx.x;
    if (e >= EG) return;
    float d = D[e] * (1.0f / 6.0f);
    float d2 = d * d, d4 = d2 * d2, d5 = d4 * d, d6 = d5 * d, d7 = d6 * d;
    float env = 1.0f - 21.0f * d5 + 35.0f * d6 - 15.0f * d7;
    if (d >= 1.0f) env = 0.0f;
    float r[16];
#pragma unroll
    for (int i = 0; i < 16; i++) {
        float t = d - (float)i * (1.0f / 15.0f);
        r[i] = env * __expf(-112.5f * t * t);
    }
#pragma unroll
    for (int j = 0; j < 16; j++) rbf[(size_t)e * 16 + j] = f2bf(r[j]);
    for (int s = 0; s < 7; s++) {
#pragma unroll 4
        for (int i = 0; i < 16; i++) {
            float a = 0.f;
#pragma unroll
            for (int k = 0; k < 16; k++)
                a = fmaf(r[k], sW[(s * 16 + k) * 16 + i], a);
            rbfW1[(size_t)e * 112 + s * 16 + i] = a;
        }
    }
}

// ---------------------------------------------------------------------------
// spherical basis + cbf_t; OUTPUT PERMUTED: cbf[rank[t]] = value(t)
// ---------------------------------------------------------------------------
__global__ __launch_bounds__(256) void k_cbf(
    const float* __restrict__ cosphi, const int* __restrict__ id3_ca,
    const float* __restrict__ rbfW1, const int* __restrict__ rank,
    bf16t* __restrict__ cbf)
{
    int t = blockIdx.x * 256 + threadIdx.x;
    if (t >= TT) return;
    float c = cosphi[t];
    const float norm[7] = {0.28209479177387814f, 0.4886025119029199f, 0.6307831305050401f,
                           0.7463526651802308f, 0.8462843753216345f, 0.935414346693485f,
                           1.0171072362820548f};
    float y[7];
    float pm2 = 1.0f, pm1 = c;
    y[0] = norm[0];
    y[1] = norm[1] * c;
    for (int l = 2; l < 7; l++) {
        float p = ((2.0f * l - 1.0f) * c * pm1 - (l - 1.0f) * pm2) / (float)l;
        y[l] = norm[l] * p;
        pm2 = pm1; pm1 = p;
    }
    int e = id3_ca[t];
    const float* __restrict__ w = rbfW1 + (size_t)e * 112;
    float out[16];
#pragma unroll
    for (int i = 0; i < 16; i++) out[i] = 0.f;
#pragma unroll
    for (int s = 0; s < 7; s++) {
        float ys = y[s];
#pragma unroll
        for (int i = 0; i < 16; i++) out[i] = fmaf(ys, w[s * 16 + i], out[i]);
    }
    int p = rank[t];
#pragma unroll
    for (int i = 0; i < 16; i++) cbf[(size_t)p * 16 + i] = f2bf(out[i]);
}

// ---------------------------------------------------------------------------
__global__ __launch_bounds__(256) void k_hgather(
    const float* __restrict__ emb, const int* __restrict__ Z, bf16t* __restrict__ h)
{
    int i = blockIdx.x * 256 + threadIdx.x;
    if (i < NATOM * 128) {
        int n = i >> 7, j = i & 127;
        h[i] = f2bf(emb[(size_t)Z[n] * 128 + j]);
    }
}

// ---------------------------------------------------------------------------
// mgemm3: LDS-staged MFMA GEMM, 2x2 wave grid, FRxFC frags/wave (small tiles)
// ---------------------------------------------------------------------------
template <typename TA, int FR, int FC, int EPI>
__global__ __launch_bounds__(256) void mgemm3(
    const TA* __restrict__ A, const bf16t* __restrict__ BT,
    bf16t* __restrict__ C, const bf16t* __restrict__ skip,
    int M, int N, int K)
{
    constexpr int ROWS = 2 * FR * 16;
    constexpr int COLS = 2 * FC * 16;
    __shared__ __align__(16) ushort As[ROWS][40];
    __shared__ __align__(16) ushort Bs[COLS][40];
    const int tid = threadIdx.x, wave = tid >> 6, lane = tid & 63;
    const int waveR = wave >> 1, waveC = wave & 1;
    const int rowBase = blockIdx.y * ROWS, colBase = blockIdx.x * COLS;

    const int sar = tid >> 1, sak = (tid & 1) << 4;
    int agr = rowBase + sar; if (agr >= M) agr = M - 1;
    int sbc, sbk;
    if constexpr (COLS == 128) { sbc = tid >> 1; sbk = (tid & 1) << 4; }
    else                       { sbc = tid >> 2; sbk = (tid & 3) << 3; }

    f32x4 zv = {0.f, 0.f, 0.f, 0.f};
    f32x4 acc[FR][FC];
#pragma unroll
    for (int f = 0; f < FR; f++)
#pragma unroll
        for (int q = 0; q < FC; q++) acc[f][q] = zv;

    const int arow0 = waveR * FR * 16 + (lane & 15);
    const int bcol0 = waveC * FC * 16 + (lane & 15);
    const int kd = (lane >> 4) << 3;

    u16x8 a0, a1, b0, b1;
    auto loadA = [&](int k0) {
        if constexpr (sizeof(TA) == 2) {
            const u16x8* s = (const u16x8*)((const bf16t*)A + (size_t)agr * K + k0 + sak);
            a0 = s[0]; a1 = s[1];
        } else {
            const float4* s = (const float4*)((const float*)A + (size_t)agr * K + k0 + sak);
            a0 = cvt8(s[0], s[1]); a1 = cvt8(s[2], s[3]);
        }
    };
    auto loadB = [&](int k0) {
        const u16x8* s = (const u16x8*)(BT + (size_t)(colBase + sbc) * K + k0 + sbk);
        b0 = s[0];
        if constexpr (COLS == 128) b1 = s[1];
    };
    loadA(0); loadB(0);
    for (int k0 = 0; k0 < K; k0 += 32) {
        __syncthreads();
        *(u16x8*)&As[sar][sak] = a0;
        *(u16x8*)&As[sar][sak + 8] = a1;
        *(u16x8*)&Bs[sbc][sbk] = b0;
        if constexpr (COLS == 128) *(u16x8*)&Bs[sbc][sbk + 8] = b1;
        __syncthreads();
        if (k0 + 32 < K) { loadA(k0 + 32); loadB(k0 + 32); }
        u16x8 af[FR], bf[FC];
#pragma unroll
        for (int f = 0; f < FR; f++) af[f] = *(const u16x8*)&As[arow0 + f * 16][kd];
#pragma unroll
        for (int q = 0; q < FC; q++) bf[q] = *(const u16x8*)&Bs[bcol0 + q * 16][kd];
#pragma unroll
        for (int f = 0; f < FR; f++)
#pragma unroll
            for (int q = 0; q < FC; q++)
                acc[f][q] = __builtin_amdgcn_mfma_f32_16x16x32_bf16(
                    *(s16x8*)&af[f], *(s16x8*)&bf[q], acc[f][q], 0, 0, 0);
    }

    const int rB = rowBase + waveR * FR * 16 + ((lane >> 4) << 2);
    const int cB = colBase + waveC * FC * 16 + (lane & 15);
#pragma unroll
    for (int f = 0; f < FR; f++) {
#pragma unroll
        for (int r = 0; r < 4; r++) {
            int row = rB + f * 16 + r;
            if (row >= M) continue;
#pragma unroll
            for (int q = 0; q < FC; q++) {
                int col = cB + q * 16;
                float v = acc[f][q][r];
                if (EPI == 1) {
                    C[(size_t)row * N + col] = f2bf(ssilu(v));
                } else {
                    float sk = bf2f(skip[(size_t)row * N + col]);
                    C[(size_t)row * N + col] = f2bf((sk + ssilu(v)) * INV_SQRT2f);
                }
            }
        }
    }
}

// ---------------------------------------------------------------------------
// mgemm4: 256-row tile, COLS=2*FC*16 (=128). Each wave: 128 rows x 64 cols
// (8x4 frags) -> 12 ds_read_b128 vs 32 MFMA per K-step: MFMA-bound. ssilu epi.
// ---------------------------------------------------------------------------
template <typename TA, int FC>
__global__ __launch_bounds__(256) void mgemm4(
    const TA* __restrict__ A, const bf16t* __restrict__ BT,
    bf16t* __restrict__ C, int M, int N, int K)
{
    constexpr int COLS = 2 * FC * 16;
    __shared__ __align__(16) ushort As[256][40];
    __shared__ __align__(16) ushort Bs[COLS][40];
    const int tid = threadIdx.x, wave = tid >> 6, lane = tid & 63;
    const int waveR = wave >> 1, waveC = wave & 1;
    const int rowBase = blockIdx.y * 256, colBase = blockIdx.x * COLS;

    int agr = rowBase + tid; if (agr >= M) agr = M - 1;
    const int sbc = tid >> 1, sbk = (tid & 1) << 4;

    f32x4 zv = {0.f, 0.f, 0.f, 0.f};
    f32x4 acc[8][FC];
#pragma unroll
    for (int f = 0; f < 8; f++)
#pragma unroll
        for (int q = 0; q < FC; q++) acc[f][q] = zv;

    const int arow0 = waveR * 128 + (lane & 15);
    const int bcol0 = waveC * FC * 16 + (lane & 15);
    const int kd = (lane >> 4) << 3;

    u16x8 a[4], b0, b1;
    auto loadA = [&](int k0) {
        if constexpr (sizeof(TA) == 2) {
            const u16x8* s = (const u16x8*)((const bf16t*)A + (size_t)agr * K + k0);
            a[0] = s[0]; a[1] = s[1]; a[2] = s[2]; a[3] = s[3];
        } else {
            const float4* s = (const float4*)((const float*)A + (size_t)agr * K + k0);
            a[0] = cvt8(s[0], s[1]); a[1] = cvt8(s[2], s[3]);
            a[2] = cvt8(s[4], s[5]); a[3] = cvt8(s[6], s[7]);
        }
    };
    auto loadB = [&](int k0) {
        const u16x8* s = (const u16x8*)(BT + (size_t)(colBase + sbc) * K + k0 + sbk);
        b0 = s[0]; b1 = s[1];
    };
    loadA(0); loadB(0);
    for (int k0 = 0; k0 < K; k0 += 32) {
        __syncthreads();
        *(u16x8*)&As[tid][0] = a[0];
        *(u16x8*)&As[tid][8] = a[1];
        *(u16x8*)&As[tid][16] = a[2];
        *(u16x8*)&As[tid][24] = a[3];
        *(u16x8*)&Bs[sbc][sbk] = b0;
        *(u16x8*)&Bs[sbc][sbk + 8] = b1;
        __syncthreads();
        if (k0 + 32 < K) { loadA(k0 + 32); loadB(k0 + 32); }
        u16x8 af[8], bf[FC];
#pragma unroll
        for (int f = 0; f < 8; f++) af[f] = *(const u16x8*)&As[arow0 + f * 16][kd];
#pragma unroll
        for (int q = 0; q < FC; q++) bf[q] = *(const u16x8*)&Bs[bcol0 + q * 16][kd];
#pragma unroll
        for (int f = 0; f < 8; f++)
#pragma unroll
            for (int q = 0; q < FC; q++)
                acc[f][q] = __builtin_amdgcn_mfma_f32_16x16x32_bf16(
                    *(s16x8*)&af[f], *(s16x8*)&bf[q], acc[f][q], 0, 0, 0);
    }

    const int rB = rowBase + waveR * 128 + ((lane >> 4) << 2);
    const int cB = colBase + waveC * FC * 16 + (lane & 15);
#pragma unroll
    for (int f = 0; f < 8; f++) {
#pragma unroll
        for (int r = 0; r < 4; r++) {
            int row = rB + f * 16 + r;
            if (row >= M) continue;
#pragma unroll
            for (int q = 0; q < FC; q++)
                C[(size_t)row * N + cB + q * 16] = f2bf(ssilu(acc[f][q][r]));
        }
    }
}

// ---------------------------------------------------------------------------
// mgemm_res: fused residual layer. 64-row tile, N=FCC*32 (256 or 128), K=N.
// ---------------------------------------------------------------------------
template <int FCC, int EPIOUT>
__global__ __launch_bounds__(256) void mgemm_res(
    const bf16t* __restrict__ A, const bf16t* __restrict__ BT0,
    const bf16t* __restrict__ BT1, bf16t* __restrict__ C,
    const bf16t* __restrict__ add2, int M)
{
    constexpr int N = FCC * 32;
    __shared__ __align__(16) ushort As[64][40];
    __shared__ __align__(16) ushort Bs[N][40];
    __shared__ __align__(16) ushort inter[64][N + 8];
    const int tid = threadIdx.x, wave = tid >> 6, lane = tid & 63;
    const int waveR = wave >> 1, waveC = wave & 1;
    const int rowBase = blockIdx.x * 64;

    const int sar = tid >> 2, sak = (tid & 3) << 3;
    int agr = rowBase + sar; if (agr >= M) agr = M - 1;
    const int sbc = tid >> 2, sbk = (tid & 3) << 3;

    const int arow0 = waveR * 32 + (lane & 15);
    const int bcol0 = waveC * FCC * 16 + (lane & 15);
    const int kd = (lane >> 4) << 3;

    f32x4 zv = {0.f, 0.f, 0.f, 0.f};
    f32x4 acc[2][FCC];
#pragma unroll
    for (int f = 0; f < 2; f++)
#pragma unroll
        for (int q = 0; q < FCC; q++) acc[f][q] = zv;

    u16x8 aR, bR[FCC / 2];
    auto loadA = [&](int k0) {
        aR = *(const u16x8*)(A + (size_t)agr * N + k0 + sak);
    };
    auto loadB = [&](const bf16t* BT, int k0) {
#pragma unroll
        for (int j = 0; j < FCC / 2; j++)
            bR[j] = *(const u16x8*)(BT + (size_t)(sbc + j * 64) * N + k0 + sbk);
    };

    // ---- phase 1 ----
    loadA(0); loadB(BT0, 0);
    for (int k0 = 0; k0 < N; k0 += 32) {
        __syncthreads();
        *(u16x8*)&As[sar][sak] = aR;
#pragma unroll
        for (int j = 0; j < FCC / 2; j++) *(u16x8*)&Bs[sbc + j * 64][sbk] = bR[j];
        __syncthreads();
        if (k0 + 32 < N) { loadA(k0 + 32); loadB(BT0, k0 + 32); }
        else             { loadB(BT1, 0); }
        u16x8 af0 = *(const u16x8*)&As[arow0][kd];
        u16x8 af1 = *(const u16x8*)&As[arow0 + 16][kd];
        u16x8 bf[FCC];
#pragma unroll
        for (int q = 0; q < FCC; q++) bf[q] = *(const u16x8*)&Bs[bcol0 + q * 16][kd];
#pragma unroll
        for (int q = 0; q < FCC; q++) {
            acc[0][q] = __builtin_amdgcn_mfma_f32_16x16x32_bf16(
                *(s16x8*)&af0, *(s16x8*)&bf[q], acc[0][q], 0, 0, 0);
            acc[1][q] = __builtin_amdgcn_mfma_f32_16x16x32_bf16(
                *(s16x8*)&af1, *(s16x8*)&bf[q], acc[1][q], 0, 0, 0);
        }
    }
    {
        const int rL = waveR * 32 + ((lane >> 4) << 2);
        const int cL = waveC * FCC * 16 + (lane & 15);
#pragma unroll
        for (int f = 0; f < 2; f++)
#pragma unroll
            for (int r = 0; r < 4; r++)
#pragma unroll
                for (int q = 0; q < FCC; q++)
                    inter[rL + f * 16 + r][cL + q * 16] = f2bf(ssilu(acc[f][q][r]));
    }
#pragma unroll
    for (int f = 0; f < 2; f++)
#pragma unroll
        for (int q = 0; q < FCC; q++) acc[f][q] = zv;

    // ---- phase 2 ----
    for (int k0 = 0; k0 < N; k0 += 32) {
        __syncthreads();
#pragma unroll
        for (int j = 0; j < FCC / 2; j++) *(u16x8*)&Bs[sbc + j * 64][sbk] = bR[j];
        __syncthreads();
        if (k0 + 32 < N) loadB(BT1, k0 + 32);
        u16x8 af0 = *(const u16x8*)&inter[arow0][k0 + kd];
        u16x8 af1 = *(const u16x8*)&inter[arow0 + 16][k0 + kd];
        u16x8 bf[FCC];
#pragma unroll
        for (int q = 0; q < FCC; q++) bf[q] = *(const u16x8*)&Bs[bcol0 + q * 16][kd];
#pragma unroll
        for (int q = 0; q < FCC; q++) {
            acc[0][q] = __builtin_amdgcn_mfma_f32_16x16x32_bf16(
                *(s16x8*)&af0, *(s16x8*)&bf[q], acc[0][q], 0, 0, 0);
            acc[1][q] = __builtin_amdgcn_mfma_f32_16x16x32_bf16(
                *(s16x8*)&af1, *(s16x8*)&bf[q], acc[1][q], 0, 0, 0);
        }
    }

    const int rB = rowBase + waveR * 32 + ((lane >> 4) << 2);
    const int cB = waveC * FCC * 16 + (lane & 15);
#pragma unroll
    for (int f = 0; f < 2; f++) {
#pragma unroll
        for (int r = 0; r < 4; r++) {
            int row = rB + f * 16 + r;
            if (row >= M) continue;
#pragma unroll
            for (int q = 0; q < FCC; q++) {
                int col = cB + q * 16;
                float sk = bf2f(A[(size_t)row * N + col]);
                float y = (sk + ssilu(acc[f][q][r])) * INV_SQRT2f;
                if (EPIOUT == 1) y = (y + bf2f(add2[(size_t)row * N + col])) * INV_SQRT2f;
                C[(size_t)row * N + col] = f2bf(y);
            }
        }
    }
}

// ---------------------------------------------------------------------------
// mgemmA1: concat-gather A MFMA GEMM. 256-row tile, COLS=128 (8x4 frags/wave).
// A row r = concat(hA[gS[r]], hA[gT[r]], X[r,:w2]); BT stride KP.
// ---------------------------------------------------------------------------
__global__ __launch_bounds__(256) void mgemmA1(
    const bf16t* __restrict__ BT, bf16t* __restrict__ C,
    int M, int N, int K, int KP,
    const bf16t* __restrict__ hA, const int* __restrict__ gS,
    const int* __restrict__ gT, const bf16t* __restrict__ X, int w2)
{
    __shared__ __align__(16) ushort As[256][40];
    __shared__ __align__(16) ushort Bs[128][40];
    const int tid = threadIdx.x, wave = tid >> 6, lane = tid & 63;
    const int waveR = wave >> 1, waveC = wave & 1;
    const int rowBase = blockIdx.y * 256, colBase = blockIdx.x * 128;

    int agr = rowBase + tid; if (agr >= M) agr = M - 1;
    const int ia = gS[agr], ibx = gT[agr];
    const int sbc = tid >> 1, sbk = (tid & 1) << 4;

    f32x4 zv = {0.f, 0.f, 0.f, 0.f};
    f32x4 acc[8][4];
#pragma unroll
    for (int f = 0; f < 8; f++)
#pragma unroll
        for (int q = 0; q < 4; q++) acc[f][q] = zv;

    const int arow0 = waveR * 128 + (lane & 15);
    const int bcol0 = waveC * 64 + (lane & 15);
    const int kd = (lane >> 4) << 3;

    u16x8 a[4], b0, b1;
    auto loadA = [&](int k0) {
#pragma unroll
        for (int h = 0; h < 2; h++) {
            int kk = k0 + 16 * h;
            u16x8 t0{}, t1{};
            if (kk < 128) {
                const u16x8* s = (const u16x8*)(hA + (size_t)ia * 128 + kk);
                t0 = s[0]; t1 = s[1];
            } else if (kk < 256) {
                const u16x8* s = (const u16x8*)(hA + (size_t)ibx * 128 + (kk - 128));
                t0 = s[0]; t1 = s[1];
            } else if (kk < K && kk - 256 < w2) {
                const u16x8* s = (const u16x8*)(X + (size_t)agr * w2 + (kk - 256));
                t0 = s[0]; t1 = s[1];
            }
            a[2 * h] = t0; a[2 * h + 1] = t1;
        }
    };
    auto loadB = [&](int k0) {
        const u16x8* s = (const u16x8*)(BT + (size_t)(colBase + sbc) * KP + k0 + sbk);
        b0 = s[0]; b1 = s[1];
    };
    loadA(0); loadB(0);
    for (int k0 = 0; k0 < K; k0 += 32) {
        __syncthreads();
        *(u16x8*)&As[tid][0] = a[0];
        *(u16x8*)&As[tid][8] = a[1];
        *(u16x8*)&As[tid][16] = a[2];
        *(u16x8*)&As[tid][24] = a[3];
        *(u16x8*)&Bs[sbc][sbk] = b0;
        *(u16x8*)&Bs[sbc][sbk + 8] = b1;
        __syncthreads();
        if (k0 + 32 < K) { loadA(k0 + 32); loadB(k0 + 32); }
        u16x8 af[8], bf[4];
#pragma unroll
        for (int f = 0; f < 8; f++) af[f] = *(const u16x8*)&As[arow0 + f * 16][kd];
#pragma unroll
        for (int q = 0; q < 4; q++) bf[q] = *(const u16x8*)&Bs[bcol0 + q * 16][kd];
#pragma unroll
        for (int f = 0; f < 8; f++)
#pragma unroll
            for (int q = 0; q < 4; q++)
                acc[f][q] = __builtin_amdgcn_mfma_f32_16x16x32_bf16(
                    *(s16x8*)&af[f], *(s16x8*)&bf[q], acc[f][q], 0, 0, 0);
    }

    const int rB = rowBase + waveR * 128 + ((lane >> 4) << 2);
    const int cB = colBase + waveC * 64 + (lane & 15);
#pragma unroll
    for (int f = 0; f < 8; f++) {
#pragma unroll
        for (int r = 0; r < 4; r++) {
            int row = rB + f * 16 + r;
            if (row >= M) continue;
#pragma unroll
            for (int q = 0; q < 4; q++)
                C[(size_t)row * N + cB + q * 16] = f2bf(ssilu(acc[f][q][r]));
        }
    }
}

// ---------------------------------------------------------------------------
// fused up-projection + skip
// ---------------------------------------------------------------------------
__global__ __launch_bounds__(256) void mgemm_up(
    const float* __restrict__ A, const bf16t* __restrict__ BTca,
    const bf16t* __restrict__ BTac, bf16t* __restrict__ C,
    const bf16t* __restrict__ skip, int M)
{
    constexpr int K = 64, N = 256;
    __shared__ __align__(16) ushort As[128][40];
    __shared__ __align__(16) ushort Bs[2][64][40];
    const int tid = threadIdx.x, wave = tid >> 6, lane = tid & 63;
    const int waveR = wave >> 1, waveC = wave & 1;
    const int rowBase = blockIdx.y * 128, colBase = blockIdx.x * 64;

    const int sar = tid >> 1, sak = (tid & 1) << 4;
    int agr = rowBase + sar; if (agr >= M) agr = M - 1;
    const int sbc = tid >> 2, sbk = (tid & 3) << 3;

    f32x4 zv = {0.f, 0.f, 0.f, 0.f};
    f32x4 accA[4][2], accB[4][2];
#pragma unroll
    for (int f = 0; f < 4; f++)
#pragma unroll
        for (int q = 0; q < 2; q++) { accA[f][q] = zv; accB[f][q] = zv; }

    const int arow0 = waveR * 64 + (lane & 15);
    const int bcol0 = waveC * 32 + (lane & 15);
    const int kd = (lane >> 4) << 3;

    u16x8 a0, a1, bA, bB;
    auto loadA = [&](int k0) {
        const float4* s = (const float4*)(A + (size_t)agr * K + k0 + sak);
        a0 = cvt8(s[0], s[1]); a1 = cvt8(s[2], s[3]);
    };
    auto loadB = [&](int k0) {
        bA = *(const u16x8*)(BTca + (size_t)(colBase + sbc) * K + k0 + sbk);
        bB = *(const u16x8*)(BTac + (size_t)(colBase + sbc) * K + k0 + sbk);
    };
    loadA(0); loadB(0);
    for (int k0 = 0; k0 < K; k0 += 32) {
        __syncthreads();
        *(u16x8*)&As[sar][sak] = a0;
        *(u16x8*)&As[sar][sak + 8] = a1;
        *(u16x8*)&Bs[0][sbc][sbk] = bA;
        *(u16x8*)&Bs[1][sbc][sbk] = bB;
        __syncthreads();
        if (k0 + 32 < K) { loadA(k0 + 32); loadB(k0 + 32); }
        u16x8 af[4], bfA[2], bfB[2];
#pragma unroll
        for (int f = 0; f < 4; f++) af[f] = *(const u16x8*)&As[arow0 + f * 16][kd];
#pragma unroll
        for (int q = 0; q < 2; q++) {
            bfA[q] = *(const u16x8*)&Bs[0][bcol0 + q * 16][kd];
            bfB[q] = *(const u16x8*)&Bs[1][bcol0 + q * 16][kd];
        }
#pragma unroll
        for (int f = 0; f < 4; f++)
#pragma unroll
            for (int q = 0; q < 2; q++) {
                accA[f][q] = __builtin_amdgcn_mfma_f32_16x16x32_bf16(
                    *(s16x8*)&af[f], *(s16x8*)&bfA[q], accA[f][q], 0, 0, 0);
                accB[f][q] = __builtin_amdgcn_mfma_f32_16x16x32_bf16(
                    *(s16x8*)&af[f], *(s16x8*)&bfB[q], accB[f][q], 0, 0, 0);
            }
    }

    const int rB = rowBase + waveR * 64 + ((lane >> 4) << 2);
    const int cB = colBase + waveC * 32 + (lane & 15);
#pragma unroll
    for (int f = 0; f < 4; f++) {
#pragma unroll
        for (int r = 0; r < 4; r++) {
            int row = rB + f * 16 + r;
            if (row >= M) continue;
#pragma unroll
            for (int q = 0; q < 2; q++) {
                int col = cB + q * 16;
                float v = (ssilu(accA[f][q][r]) + ssilu(accB[f][q][r ^ 1])) * INV_SQRT2f;
                float y = (bf2f(skip[(size_t)row * N + col]) + v) * INV_SQRT2f;
                C[(size_t)row * N + col] = f2bf(y);
            }
        }
    }
}

// ---------------------------------------------------------------------------
// MFMA bilinear v5: sorted triplets; W_i LDS-staged with double-buffer.
// ---------------------------------------------------------------------------
__global__ __launch_bounds__(256) void k_bilinear_m(
    const bf16t* __restrict__ xtrip, const bf16t* __restrict__ cbf,
    const bf16t* __restrict__ WT,
    const int* __restrict__ ba_s, const int* __restrict__ ca_s,
    float* __restrict__ seg)
{
    __shared__ __align__(16) ushort xs[64][72];
    __shared__ ushort cbs[64][16];
    __shared__ int cas[64];
    __shared__ __align__(16) ushort ws[2][4096];
    __shared__ __align__(16) float ts[64][65];
    const int tid = threadIdx.x, wave = tid >> 6, lane = tid & 63;
    const int t0 = blockIdx.x * 64;
    {
        int r = tid >> 2, q = (tid & 3) << 4;
        int ba = ba_s[t0 + r];
        const u16x8* src = (const u16x8*)(xtrip + (size_t)ba * 64 + q);
        *(u16x8*)&xs[r][q] = src[0];
        *(u16x8*)&xs[r][q + 8] = src[1];
    }
    if (tid < 64) cas[tid] = ca_s[t0 + tid];
    {
        int e = tid << 2; int r = e >> 4, c = e & 15;
        *(ushort4*)&cbs[r][c] = *(const ushort4*)(cbf + (size_t)(t0 + r) * 16 + c);
    }
    u16x8 g0, g1;
    {
        const u16x8* s = (const u16x8*)(WT + (size_t)tid * 16);
        *(u16x8*)&ws[0][tid * 16] = s[0];
        *(u16x8*)&ws[0][tid * 16 + 8] = s[1];
        const u16x8* s1 = (const u16x8*)(WT + 4096 + (size_t)tid * 16);
        g0 = s1[0]; g1 = s1[1];
    }
    __syncthreads();
    const int kd = (lane >> 4) << 3;
    u16x8 a0 = *(const u16x8*)(&xs[wave * 16 + (lane & 15)][kd]);
    u16x8 a1 = *(const u16x8*)(&xs[wave * 16 + (lane & 15)][32 + kd]);
    const int rowo = wave * 16 + ((lane >> 4) << 2);
    const int chb = lane >> 4, colw = lane & 15;

    float tot[4][4];
#pragma unroll
    for (int a = 0; a < 4; a++)
#pragma unroll
        for (int b = 0; b < 4; b++) tot[a][b] = 0.f;

    for (int i = 0; i < 16; i++) {
        const int cur = i & 1;
        if (i < 15) {
            *(u16x8*)&ws[cur ^ 1][tid * 16] = g0;
            *(u16x8*)&ws[cur ^ 1][tid * 16 + 8] = g1;
        }
        const ushort* wb = ws[cur];
        f32x4 zv = {0.f, 0.f, 0.f, 0.f};
        f32x4 p[4] = {zv, zv, zv, zv};
#pragma unroll
        for (int fc = 0; fc < 4; fc++) {
            u16x8 b0 = *(const u16x8*)&wb[((chb * 64) + colw + fc * 16) * 8];
            u16x8 b1 = *(const u16x8*)&wb[(((4 + chb) * 64) + colw + fc * 16) * 8];
            p[fc] = __builtin_amdgcn_mfma_f32_16x16x32_bf16(
                *(s16x8*)&a0, *(s16x8*)&b0, p[fc], 0, 0, 0);
            p[fc] = __builtin_amdgcn_mfma_f32_16x16x32_bf16(
                *(s16x8*)&a1, *(s16x8*)&b1, p[fc], 0, 0, 0);
        }
#pragma unroll
        for (int r = 0; r < 4; r++) {
            float s = bf2f(cbs[rowo + r][i]);
#pragma unroll
            for (int fc = 0; fc < 4; fc++) tot[fc][r] += s * p[fc][r];
        }
        if (i < 14) {
            const u16x8* s = (const u16x8*)(WT + (size_t)(i + 2) * 4096 + (size_t)tid * 16);
            g0 = s[0]; g1 = s[1];
        }
        __syncthreads();
    }
#pragma unroll
    for (int r = 0; r < 4; r++)
#pragma unroll
        for (int fc = 0; fc < 4; fc++)
            ts[rowo + r][fc * 16 + (lane & 15)] = tot[fc][r];
    __syncthreads();
    {
        int q = tid >> 6, c = tid & 63;
        float s = 0.f;
        int cur = cas[q * 16];
#pragma unroll 1
        for (int r = q * 16; r < q * 16 + 16; r++) {
            int ca = cas[r];
            if (ca != cur) {
                atomicAdd(&seg[(size_t)cur * 64 + c], s);
                s = 0.f; cur = ca;
            }
            s += ts[r][c];
        }
        atomicAdd(&seg[(size_t)cur * 64 + c], s);
    }
}

// ---------------------------------------------------------------------------
// per-edge multiply by (rbf[e,16] @ Wc[16,256]) -> bf16, 16 edges per block,
// Wc staged in LDS once (16x less L2 traffic).
// ---------------------------------------------------------------------------
__global__ __launch_bounds__(256) void k_mulproj(
    const bf16t* __restrict__ in, const bf16t* __restrict__ rvec,
    const float* __restrict__ Wp, bf16t* __restrict__ out)
{
    __shared__ float sW[4096];
    __shared__ float sr[256];
    const int j = threadIdx.x;
    const int e0 = blockIdx.x * 16;
    for (int t = j; t < 4096; t += 256) sW[t] = Wp[t];
    sr[j] = bf2f(rvec[(size_t)e0 * 16 + j]);
    __syncthreads();
#pragma unroll 4
    for (int g = 0; g < 16; g++) {
        float p = 0.f;
#pragma unroll
        for (int k = 0; k < 16; k++) p = fmaf(sr[g * 16 + k], sW[k * 256 + j], p);
        size_t e = (size_t)(e0 + g);
        out[e * 256 + j] = f2bf(bf2f(in[e * 256 + j]) * p);
    }
}

// ---------------------------------------------------------------------------
// LN(m row) * (rbf @ Wc) -> bf16, 16 edges per block, Wc in LDS
// ---------------------------------------------------------------------------
__global__ __launch_bounds__(256) void k_ln_proj(
    const bf16t* __restrict__ m, const float* __restrict__ lnw,
    const float* __restrict__ lnb, const bf16t* __restrict__ rvec,
    const float* __restrict__ Wp, bf16t* __restrict__ out)
{
    __shared__ float sW[4096];
    __shared__ float sr[256];
    __shared__ float red[8];
    const int j = threadIdx.x;
    const int e0 = blockIdx.x * 16;
    for (int t = j; t < 4096; t += 256) sW[t] = Wp[t];
    sr[j] = bf2f(rvec[(size_t)e0 * 16 + j]);
    const float lw = lnw[j], lb = lnb[j];
    __syncthreads();
    const int wid = j >> 6, lane = j & 63;
    for (int g = 0; g < 16; g++) {
        size_t e = (size_t)(e0 + g);
        float v = bf2f(m[e * 256 + j]);
        float s = v, s2 = v * v;
#pragma unroll
        for (int off = 32; off > 0; off >>= 1) {
            s += __shfl_xor(s, off);
            s2 += __shfl_xor(s2, off);
        }
        if (lane == 0) { red[wid] = s; red[4 + wid] = s2; }
        __syncthreads();
        float tot = red[0] + red[1] + red[2] + red[3];
        float tot2 = red[4] + red[5] + red[6] + red[7];
        float mu = tot * (1.f / 256.f);
        float var = tot2 * (1.f / 256.f) - mu * mu;
        float ln = (v - mu) * rsqrtf(var + 1e-5f) * lw + lb;
        float p = 0.f;
#pragma unroll
        for (int k = 0; k < 16; k++) p = fmaf(sr[g * 16 + k], sW[k * 256 + j], p);
        out[e * 256 + j] = f2bf(ln * p);
        __syncthreads();
    }
}

// ---------------------------------------------------------------------------
__global__ __launch_bounds__(128) void k_ln_acc(
    const bf16t* __restrict__ x, const float* __restrict__ w,
    const float* __restrict__ b, float* __restrict__ out)
{
    int n = blockIdx.x;
    int j = threadIdx.x;
    __shared__ float red[4];
    float v = bf2f(x[(size_t)n * 128 + j]);
    float s = v, s2 = v * v;
#pragma unroll
    for (int off = 32; off > 0; off >>= 1) {
        s += __shfl_xor(s, off);
        s2 += __shfl_xor(s2, off);
    }
    int wid = j >> 6, lane = j & 63;
    if (lane == 0) { red[wid] = s; red[2 + wid] = s2; }
    __syncthreads();
    float tot = red[0] + red[1];
    float tot2 = red[2] + red[3];
    float mu = tot * (1.f / 128.f);
    float var = tot2 * (1.f / 128.f) - mu * mu;
    out[(size_t)n * 128 + j] += (v - mu) * rsqrtf(var + 1e-5f) * w[j] + b[j];
}

// ---------------------------------------------------------------------------
typedef bf16t T;
static bool try_run(void* const* d_in, void* d_out, void* d_ws, size_t ws_size, hipStream_t stream)
{
    const float* D            = (const float*)d_in[0];
    const float* cosphi       = (const float*)d_in[1];
    const float* atom_emb     = (const float*)d_in[2];
    const float* W_rbf3       = (const float*)d_in[3];
    const float* W_rbf_h      = (const float*)d_in[4];
    const float* W_rbf_out    = (const float*)d_in[5];
    const float* W_cbf_down   = (const float*)d_in[6];
    const float* W_edge_emb   = (const float*)d_in[7];
    const float* ib_dense_ca  = (const float*)d_in[8];
    const float* ib_trip_dense_ba = (const float*)d_in[9];
    const float* ib_trip_mlp_rbf  = (const float*)d_in[10];
    const float* ib_trip_down     = (const float*)d_in[11];
    const float* ib_trip_bilinear = (const float*)d_in[12];
    const float* ib_trip_up_ca    = (const float*)d_in[13];
    const float* ib_trip_up_ac    = (const float*)d_in[14];
    const float* ib_res_before    = (const float*)d_in[15];
    const float* ib_res_after     = (const float*)d_in[16];
    const float* ib_atom_dense_rbf = (const float*)d_in[17];
    const float* ib_atom_dense1    = (const float*)d_in[18];
    const float* ib_atom_res       = (const float*)d_in[19];
    const float* ib_concat_dense   = (const float*)d_in[20];
    const float* ib_res_m          = (const float*)d_in[21];
    const float* ob_dense_rbf      = (const float*)d_in[22];
    const float* ob_dense1         = (const float*)d_in[23];
    const float* ob_res            = (const float*)d_in[24];
    const float* ln_m_w            = (const float*)d_in[25];
    const float* ln_m_b            = (const float*)d_in[26];
    const float* ln_E_w            = (const float*)d_in[27];
    const float* ln_E_b            = (const float*)d_in[28];
    const int* Z       = (const int*)d_in[29];
    const int* idx_s   = (const int*)d_in[30];
    const int* idx_t   = (const int*)d_in[31];
    const int* id3_ba  = (const int*)d_in[32];
    const int* id3_ca  = (const int*)d_in[33];

    char* base = (char*)d_ws;
    size_t off = 0;
    auto alloc = [&](size_t bytes) -> char* {
        off = (off + 255) & ~(size_t)255;
        char* p = base + off;
        off += bytes;
        return p;
    };
    T* m      = (T*)alloc((size_t)EG * 256 * 2);
    T* B1     = (T*)alloc((size_t)EG * 256 * 2);
    T* B2     = (T*)alloc((size_t)EG * 256 * 2);
    float* rbfW1 = (float*)B1;                 // alias: dead before B1 first written
    int* rank    = (int*)B2;                   // alias: dead before B2 first written
    T* rbf    = (T*)alloc((size_t)EG * 16 * 2);
    T* cbf    = (T*)alloc((size_t)TT * 16 * 2);
    bf16t* h  = (bf16t*)alloc((size_t)NATOM * 128 * 2);
    T* xtrip  = (T*)alloc((size_t)EG * 64 * 2);
    // union: seg64 f32 (bilinear) | {segN_b, At1b} bf16 | setup counters
    char* ub  = alloc((size_t)EG * 64 * 4);
    float* seg64  = (float*)ub;
    bf16t* segN_b = (bf16t*)ub;
    bf16t* At1b   = (bf16t*)(ub + (size_t)NATOM * 256 * 2);
    int* cntT  = (int*)ub;
    int* cnt2T = (int*)(ub + (size_t)EG * 4);
    int* off_ca = (int*)(ub + (size_t)2 * EG * 4);
    float* wcb = (float*)alloc((size_t)7 * 4096 * 4);
    bf16t* ar  = (bf16t*)alloc((size_t)507904 * 2);
    int* off_atom  = (int*)alloc((size_t)(NATOM + 1) * 4);
    int* ba_s      = (int*)alloc((size_t)TT * 4);
    int* ca_s      = (int*)alloc((size_t)TT * 4);
    int* csr_edges = (int*)alloc((size_t)EG * 4);
    if (off > ws_size) return false;
    float* out = (float*)d_out;

    // ---- launch helpers ----
    auto g256 = [&](const T* A, unsigned wOff, T* C) {
        dim3 grid(2, (EG + 255) / 256);
        mgemm4<T, 4><<<grid, 256, 0, stream>>>(A, ar + wOff, C, EG, 256, 256);
    };
    auto gatom1 = [&](const bf16t* A, unsigned wOff, bf16t* C) {
        dim3 grid(1, (NATOM + 127) / 128);
        mgemm3<bf16t, 4, 4, 1><<<grid, 256, 0, stream>>>(A, ar + wOff, C, nullptr, NATOM, 128, 256);
    };
    auto out_block = [&](int i, unsigned offD1, unsigned offRes) {
        k_ln_proj<<<EG / 16, 256, 0, stream>>>(m, ln_m_w + (size_t)i * 256, ln_m_b + (size_t)i * 256,
                                               rbf, wcb + (size_t)(4 + i) * 4096, B2);
        k_segsum<<<NATOM, 256, 0, stream>>>(B2, off_atom, csr_edges, segN_b);
        gatom1(segN_b, offD1, At1b);
        mgemm_res<4, 0><<<(NATOM + 63) / 64, 256, 0, stream>>>(
            At1b, ar + offRes, ar + offRes + 16384, At1b, nullptr, NATOM);
        mgemm_res<4, 0><<<(NATOM + 63) / 64, 256, 0, stream>>>(
            At1b, ar + offRes + 32768, ar + offRes + 49152, At1b, nullptr, NATOM);
        k_ln_acc<<<NATOM, 128, 0, stream>>>(At1b, ln_E_w + (size_t)i * 128, ln_E_b + (size_t)i * 128, out);
    };

    // ---- sort setup (once) ----
    hipMemsetAsync(cntT, 0, (size_t)EG * 4, stream);
    k_hist<<<(TT + 255) / 256, 256, 0, stream>>>(id3_ca, cntT, TT);
    k_scan<<<1, 1024, 0, stream>>>(cntT, off_ca, EG);
    hipMemsetAsync(cnt2T, 0, (size_t)EG * 4, stream);
    k_rank_trip<<<(TT + 255) / 256, 256, 0, stream>>>(id3_ca, id3_ba, off_ca, cnt2T,
                                                      rank, ba_s, ca_s, TT);
    hipMemsetAsync(cntT, 0, (size_t)NATOM * 4, stream);
    k_hist<<<(EG + 255) / 256, 256, 0, stream>>>(idx_t, cntT, EG);
    k_scan<<<1, 1024, 0, stream>>>(cntT, off_atom, NATOM);
    hipMemsetAsync(cnt2T, 0, (size_t)NATOM * 4, stream);
    k_rank_edge<<<(EG + 255) / 256, 256, 0, stream>>>(idx_t, off_atom, cnt2T, csr_edges, EG);

    // ---- weight combines (all 7, once) ----
    {
        WcBatch wb;
        wb.e[0] = {W_rbf3, ib_trip_mlp_rbf};
        wb.e[1] = {W_rbf3, ib_trip_mlp_rbf + 4096};
        wb.e[2] = {W_rbf_h, ib_atom_dense_rbf};
        wb.e[3] = {W_rbf_h, ib_atom_dense_rbf + 4096};
        wb.e[4] = {W_rbf_out, ob_dense_rbf};
        wb.e[5] = {W_rbf_out, ob_dense_rbf + 4096};
        wb.e[6] = {W_rbf_out, ob_dense_rbf + 8192};
        k_wcomb_batch<<<7, 256, 0, stream>>>(wb, wcb);
    }
    // ---- setup weight batch: edge_emb + out_block(0) ----
    {
        WtBatch wt{};
        wt.e[0] = {W_edge_emb, 0u, 272, 288, 256, 0};
        wt.e[1] = {ob_dense1, 73728u, 256, 256, 128, 0};
        for (int j = 0; j < 4; j++)
            wt.e[2 + j] = {ob_res + (size_t)j * 16384, 106496u + j * 16384u, 128, 128, 128, 0};
        wt.n = 6;
        k_wt_batch<<<512, 256, 0, stream>>>(wt, ar);
    }

    hipMemsetAsync(out, 0, (size_t)NATOM * 128 * 4, stream);
    k_rbf<<<(EG + 255) / 256, 256, 0, stream>>>(D, W_cbf_down, rbf, rbfW1);
    k_cbf<<<(TT + 255) / 256, 256, 0, stream>>>(cosphi, id3_ca, rbfW1, rank, cbf);
    k_hgather<<<(NATOM * 128 + 255) / 256, 256, 0, stream>>>(atom_emb, Z, h);
    {
        dim3 grid(2, (EG + 255) / 256);
        mgemmA1<<<grid, 256, 0, stream>>>(ar, m, EG, 256, 272, 288, h, idx_s, idx_t, rbf, 16);
    }
    out_block(0, 73728u, 106496u);

    for (int i = 0; i < 2; i++) {
        // ---- L1 weight batch ----
        {
            WtBatch wt{};
            wt.e[0] = {ib_dense_ca + (size_t)i * 65536, 0u, 256, 256, 256, 0};
            wt.e[1] = {ib_trip_dense_ba + (size_t)i * 65536, 65536u, 256, 256, 256, 0};
            wt.e[2] = {ib_trip_down + (size_t)i * 16384, 131072u, 256, 256, 64, 0};
            wt.e[3] = {ib_trip_bilinear + (size_t)i * 65536, 147456u, 0, 0, 0, 1};
            wt.e[4] = {ib_trip_up_ca + (size_t)i * 16384, 212992u, 64, 64, 256, 0};
            wt.e[5] = {ib_trip_up_ac + (size_t)i * 16384, 229376u, 64, 64, 256, 0};
            wt.e[6] = {ib_res_before + (size_t)i * 131072, 245760u, 256, 256, 256, 0};
            wt.e[7] = {ib_res_before + (size_t)i * 131072 + 65536, 311296u, 256, 256, 256, 0};
            wt.e[8] = {ib_res_after + (size_t)i * 131072, 376832u, 256, 256, 256, 0};
            wt.e[9] = {ib_res_after + (size_t)i * 131072 + 65536, 442368u, 256, 256, 256, 0};
            wt.n = 10;
            k_wt_batch<<<512, 256, 0, stream>>>(wt, ar);
        }
        // ---- triplet interaction ----
        g256(m, 0u, B1);        // x_ca_skip
        g256(m, 65536u, B2);    // x_ba
        k_mulproj<<<EG / 16, 256, 0, stream>>>(B2, rbf, wcb + (size_t)i * 4096, B2);
        {
            dim3 grid(1, (EG + 127) / 128);
            mgemm3<T, 4, 2, 1><<<grid, 256, 0, stream>>>(B2, ar + 131072, xtrip, nullptr, EG, 64, 256);
        }
        hipMemsetAsync(seg64, 0, (size_t)EG * 64 * 4, stream);
        k_bilinear_m<<<TT / 64, 256, 0, stream>>>(xtrip, cbf, ar + 147456, ba_s, ca_s, seg64);
        {
            dim3 grid(4, (EG + 127) / 128);
            mgemm_up<<<grid, 256, 0, stream>>>(seg64, ar + 212992, ar + 229376, B1, B1, EG);
        }
        // ---- edge update: res_before (+m add), res_after ----
        mgemm_res<8, 1><<<EG / 64, 256, 0, stream>>>(B1, ar + 245760, ar + 311296, B1, m, EG);
        mgemm_res<8, 0><<<EG / 64, 256, 0, stream>>>(B1, ar + 376832, ar + 442368, B1, nullptr, EG);
        // ---- L2 weight batch ----
        {
            WtBatch wt{};
            wt.e[0] = {ib_atom_dense1 + (size_t)i * 32768, 0u, 256, 256, 128, 0};
            for (int j = 0; j < 4; j++)
                wt.e[1 + j] = {ib_atom_res + (size_t)i * 65536 + (size_t)j * 16384,
                               32768u + j * 16384u, 128, 128, 128, 0};
            wt.e[5] = {ib_concat_dense + (size_t)i * 131072, 98304u, 512, 512, 256, 0};
            wt.e[6] = {ib_res_m + (size_t)i * 131072, 229376u, 256, 256, 256, 0};
            wt.e[7] = {ib_res_m + (size_t)i * 131072 + 65536, 294912u, 256, 256, 256, 0};
            wt.e[8] = {ob_dense1 + (size_t)(i + 1) * 32768, 360448u, 256, 256, 128, 0};
            wt.n = 9;
            k_wt_batch<<<512, 256, 0, stream>>>(wt, ar);
            WtBatch wt2{};
            for (int j = 0; j < 4; j++)
                wt2.e[j] = {ob_res + (size_t)(i + 1) * 65536 + (size_t)j * 16384,
                            393216u + j * 16384u, 128, 128, 128, 0};
            wt2.n = 4;
            k_wt_batch<<<512, 256, 0, stream>>>(wt2, ar);
        }
        // ---- atom update ----
        k_mulproj<<<EG / 16, 256, 0, stream>>>(B1, rbf, wcb + (size_t)(2 + i) * 4096, B2);
        k_segsum<<<NATOM, 256, 0, stream>>>(B2, off_atom, csr_edges, segN_b);
        gatom1(segN_b, 0u, At1b);
        mgemm_res<4, 0><<<(NATOM + 63) / 64, 256, 0, stream>>>(
            At1b, ar + 32768, ar + 49152, At1b, nullptr, NATOM);
        mgemm_res<4, 1><<<(NATOM + 63) / 64, 256, 0, stream>>>(
            At1b, ar + 65536, ar + 81920, h, h, NATOM);   // h = (h + xa)/√2
        // ---- edge embedding refresh ----
        {
            dim3 grid(2, (EG + 255) / 256);
            mgemmA1<<<grid, 256, 0, stream>>>(ar + 98304, B2, EG, 256, 512, 512, h, idx_s, idx_t, B1, 256);
        }
        // res_m residual + m update: m = (m + residual(B2))/√2
        mgemm_res<8, 1><<<EG / 64, 256, 0, stream>>>(B2, ar + 229376, ar + 294912, m, m, EG);

        out_block(i + 1, 360448u, 393216u);
    }
    return true;
}

extern "C" void kernel_launch(void* const* d_in, const int* in_sizes, int n_in,
                              void* d_out, int out_size, void* d_ws, size_t ws_size,
                              hipStream_t stream)
{
    if (try_run(d_in, d_out, d_ws, ws_size, stream)) return;
    float v = 3000.0f + (float)(ws_size >> 20);
    k_fill<<<(NATOM * 128 + 255) / 256, 256, 0, stream>>>((float*)d_out, NATOM * 128, v);
}

// Round 13
// 2623.948 us; speedup vs baseline: 1.0065x; 1.0065x over previous
//
#include <hip/hip_runtime.h>

#define NATOM 10000
#define EG    120000
#define TT    600000

#define INV_SQRT2f 0.7071067811865476f

typedef unsigned short bf16t;
typedef __attribute__((ext_vector_type(8))) short s16x8;
typedef __attribute__((ext_vector_type(8))) unsigned short u16x8;
typedef __attribute__((ext_vector_type(4))) float f32x4;

__device__ __forceinline__ float ssilu(float x) {
    return x * (1.0f / (1.0f + __expf(-x))) * (1.0f / 0.6f);
}
__device__ __forceinline__ float bf2f(unsigned short u) {
    return __uint_as_float(((unsigned)u) << 16);
}
__device__ __forceinline__ unsigned short f2bf(float f) {
    unsigned b = __float_as_uint(f);
    unsigned r = (b + 0x7FFF + ((b >> 16) & 1)) >> 16;  // RNE
    return (unsigned short)r;
}
__device__ __forceinline__ u16x8 cvt8(const float4 va, const float4 vb) {
    u16x8 r{};
    r[0] = f2bf(va.x); r[1] = f2bf(va.y); r[2] = f2bf(va.z); r[3] = f2bf(va.w);
    r[4] = f2bf(vb.x); r[5] = f2bf(vb.y); r[6] = f2bf(vb.z); r[7] = f2bf(vb.w);
    return r;
}

// ---------------------------------------------------------------------------
__global__ __launch_bounds__(256) void k_fill(float* __restrict__ o, int n, float v) {
    int i = blockIdx.x * 256 + threadIdx.x;
    if (i < n) o[i] = v;
}

// ---------------------------------------------------------------------------
// sort infrastructure (built once; indices are launch-constant)
// ---------------------------------------------------------------------------
__global__ __launch_bounds__(256) void k_hist(
    const int* __restrict__ idx, int* __restrict__ cnt, int n)
{
    int i = blockIdx.x * 256 + threadIdx.x;
    if (i < n) atomicAdd(&cnt[idx[i]], 1);
}

__global__ __launch_bounds__(1024) void k_scan(
    const int* __restrict__ cnt, int* __restrict__ off, int n)
{
    __shared__ int wsum[16];
    __shared__ int carrySh;
    if (threadIdx.x == 0) carrySh = 0;
    __syncthreads();
    const int lane = threadIdx.x & 63, wid = threadIdx.x >> 6;
    for (int base = 0; base < n; base += 8192) {
        int v[8]; int s = 0;
        int i0 = base + threadIdx.x * 8;
#pragma unroll
        for (int j = 0; j < 8; j++) { int i = i0 + j; v[j] = (i < n) ? cnt[i] : 0; s += v[j]; }
        int sc = s;
#pragma unroll
        for (int d = 1; d < 64; d <<= 1) { int t = __shfl_up(sc, d); if (lane >= d) sc += t; }
        if (lane == 63) wsum[wid] = sc;
        __syncthreads();
        int wbase = 0;
        for (int w = 0; w < 16; w++) wbase += (w < wid) ? wsum[w] : 0;
        int carry = carrySh;
        int excl = carry + wbase + (sc - s);
#pragma unroll
        for (int j = 0; j < 8; j++) { int i = i0 + j; if (i < n) off[i] = excl; excl += v[j]; }
        __syncthreads();
        if (threadIdx.x == 1023) carrySh = carry + wbase + sc;
        __syncthreads();
    }
    if (threadIdx.x == 0) off[n] = carrySh;
}

__global__ __launch_bounds__(256) void k_rank_trip(
    const int* __restrict__ id3_ca, const int* __restrict__ id3_ba,
    const int* __restrict__ off, int* __restrict__ cnt2,
    int* __restrict__ rank, int* __restrict__ ba_s, int* __restrict__ ca_s, int n)
{
    int t = blockIdx.x * 256 + threadIdx.x;
    if (t >= n) return;
    int ca = id3_ca[t];
    int p = off[ca] + atomicAdd(&cnt2[ca], 1);
    rank[t] = p;
    ba_s[p] = id3_ba[t];
    ca_s[p] = ca;
}

__global__ __launch_bounds__(256) void k_rank_edge(
    const int* __restrict__ idx, const int* __restrict__ off,
    int* __restrict__ cnt2, int* __restrict__ lst, int n)
{
    int i = blockIdx.x * 256 + threadIdx.x;
    if (i >= n) return;
    int a = idx[i];
    int p = off[a] + atomicAdd(&cnt2[a], 1);
    lst[p] = i;
}

// segment sum: out[n][256] (bf16) = sum of X rows (bf16) with target n (CSR)
__global__ __launch_bounds__(256) void k_segsum(
    const bf16t* __restrict__ X, const int* __restrict__ off,
    const int* __restrict__ lst, bf16t* __restrict__ out)
{
    int n = blockIdx.x, j = threadIdx.x;
    int b = off[n], e = off[n + 1];
    float s = 0.f;
    for (int k = b; k < e; k++) s += bf2f(X[(size_t)lst[k] * 256 + j]);
    out[(size_t)n * 256 + j] = f2bf(s);
}

// ---------------------------------------------------------------------------
// batched weight transpose: mode 0 -> BT[n][KP], mode 1 -> bilinear interleave
// ---------------------------------------------------------------------------
struct WtE { const float* src; unsigned dstOff; int K, KP, N, mode; };
struct WtBatch { WtE e[12]; int n; };

__global__ __launch_bounds__(256) void k_wt_batch(WtBatch b, bf16t* __restrict__ base)
{
    for (int i = 0; i < b.n; i++) {
        const WtE E = b.e[i];
        int total = (E.mode == 0) ? E.N * E.KP : 16 * 64 * 64;
        for (int idx = blockIdx.x * 256 + threadIdx.x; idx < total; idx += gridDim.x * 256) {
            bf16t v;
            if (E.mode == 0) {
                int n = idx / E.KP, k = idx - n * E.KP;
                v = (k < E.K) ? f2bf(E.src[(size_t)k * E.N + n]) : (bf16t)0;
            } else {
                int e8 = idx & 7, o = (idx >> 3) & 63, ch = (idx >> 9) & 7, ii = idx >> 12;
                v = f2bf(E.src[((size_t)(ch * 8 + e8) * 16 + ii) * 64 + o]);
            }
            base[E.dstOff + idx] = v;
        }
    }
}

// batched 16x16 @ 16x256 weight combines
struct WcE { const float* Wa; const float* Wb; };
struct WcBatch { WcE e[7]; };

__global__ __launch_bounds__(256) void k_wcomb_batch(WcBatch b, float* __restrict__ wcb)
{
    __shared__ float sA[256];
    int c = blockIdx.x, j = threadIdx.x;
    sA[j] = b.e[c].Wa[j];
    __syncthreads();
    const float* Wb = b.e[c].Wb;
    float* dst = wcb + (size_t)c * 4096;
#pragma unroll 4
    for (int r = 0; r < 16; r++) {
        float acc = 0.f;
#pragma unroll
        for (int k = 0; k < 16; k++) acc = fmaf(sA[r * 16 + k], Wb[k * 256 + j], acc);
        dst[r * 256 + j] = acc;
    }
}

// ---------------------------------------------------------------------------
// rbf basis + rbf_W1 (cbf down-projection)
// ---------------------------------------------------------------------------
__global__ __launch_bounds__(256) void k_rbf(
    const float* __restrict__ D, const float* __restrict__ Wc,
    bf16t* __restrict__ rbf, float* __restrict__ rbfW1)
{
    __shared__ float sW[1792];
    for (int i = threadIdx.x; i < 1792; i += 256) sW[i] = Wc[i];
    __syncthreads();
    int e = blockIdx.x * 256 + threadIdx.x;
    if (e >= EG) return;
    float d = D[e] * (1.0f / 6.0f);
    float d2 = d * d, d4 = d2 * d2, d5 = d4 * d, d6 = d5 * d, d7 = d6 * d;
    float env = 1.0f - 21.0f * d5 + 35.0f * d6 - 15.0f * d7;
    if (d >= 1.0f) env = 0.0f;
    float r[16];
#pragma unroll
    for (int i = 0; i < 16; i++) {
        float t = d - (float)i * (1.0f / 15.0f);
        r[i] = env * __expf(-112.5f * t * t);
    }
#pragma unroll
    for (int j = 0; j < 16; j++) rbf[(size_t)e * 16 + j] = f2bf(r[j]);
    for (int s = 0; s < 7; s++) {
#pragma unroll 4
        for (int i = 0; i < 16; i++) {
            float a = 0.f;
#pragma unroll
            for (int k = 0; k < 16; k++)
                a = fmaf(r[k], sW[(s * 16 + k) * 16 + i], a);
            rbfW1[(size_t)e * 112 + s * 16 + i] = a;
        }
    }
}

// ---------------------------------------------------------------------------
// spherical basis + cbf_t; OUTPUT PERMUTED: cbf[rank[t]] = value(t)
// ---------------------------------------------------------------------------
__global__ __launch_bounds__(256) void k_cbf(
    const float* __restrict__ cosphi, const int* __restrict__ id3_ca,
    const float* __restrict__ rbfW1, const int* __restrict__ rank,
    bf16t* __restrict__ cbf)
{
    int t = blockIdx.x * 256 + threadIdx.x;
    if (t >= TT) return;
    float c = cosphi[t];
    const float norm[7] = {0.28209479177387814f, 0.4886025119029199f, 0.6307831305050401f,
                           0.7463526651802308f, 0.8462843753216345f, 0.935414346693485f,
                           1.0171072362820548f};
    float y[7];
    float pm2 = 1.0f, pm1 = c;
    y[0] = norm[0];
    y[1] = norm[1] * c;
    for (int l = 2; l < 7; l++) {
        float p = ((2.0f * l - 1.0f) * c * pm1 - (l - 1.0f) * pm2) / (float)l;
        y[l] = norm[l] * p;
        pm2 = pm1; pm1 = p;
    }
    int e = id3_ca[t];
    const float* __restrict__ w = rbfW1 + (size_t)e * 112;
    float out[16];
#pragma unroll
    for (int i = 0; i < 16; i++) out[i] = 0.f;
#pragma unroll
    for (int s = 0; s < 7; s++) {
        float ys = y[s];
#pragma unroll
        for (int i = 0; i < 16; i++) out[i] = fmaf(ys, w[s * 16 + i], out[i]);
    }
    int p = rank[t];
#pragma unroll
    for (int i = 0; i < 16; i++) cbf[(size_t)p * 16 + i] = f2bf(out[i]);
}

// ---------------------------------------------------------------------------
__global__ __launch_bounds__(256) void k_hgather(
    const float* __restrict__ emb, const int* __restrict__ Z, bf16t* __restrict__ h)
{
    int i = blockIdx.x * 256 + threadIdx.x;
    if (i < NATOM * 128) {
        int n = i >> 7, j = i & 127;
        h[i] = f2bf(emb[(size_t)Z[n] * 128 + j]);
    }
}

// ---------------------------------------------------------------------------
// mgemm3: LDS-staged MFMA GEMM, 2x2 wave grid, FRxFC frags/wave (small tiles)
// ---------------------------------------------------------------------------
template <typename TA, int FR, int FC, int EPI>
__global__ __launch_bounds__(256) void mgemm3(
    const TA* __restrict__ A, const bf16t* __restrict__ BT,
    bf16t* __restrict__ C, const bf16t* __restrict__ skip,
    int M, int N, int K)
{
    constexpr int ROWS = 2 * FR * 16;
    constexpr int COLS = 2 * FC * 16;
    __shared__ __align__(16) ushort As[ROWS][40];
    __shared__ __align__(16) ushort Bs[COLS][40];
    const int tid = threadIdx.x, wave = tid >> 6, lane = tid & 63;
    const int waveR = wave >> 1, waveC = wave & 1;
    const int rowBase = blockIdx.y * ROWS, colBase = blockIdx.x * COLS;

    const int sar = tid >> 1, sak = (tid & 1) << 4;
    int agr = rowBase + sar; if (agr >= M) agr = M - 1;
    int sbc, sbk;
    if constexpr (COLS == 128) { sbc = tid >> 1; sbk = (tid & 1) << 4; }
    else                       { sbc = tid >> 2; sbk = (tid & 3) << 3; }

    f32x4 zv = {0.f, 0.f, 0.f, 0.f};
    f32x4 acc[FR][FC];
#pragma unroll
    for (int f = 0; f < FR; f++)
#pragma unroll
        for (int q = 0; q < FC; q++) acc[f][q] = zv;

    const int arow0 = waveR * FR * 16 + (lane & 15);
    const int bcol0 = waveC * FC * 16 + (lane & 15);
    const int kd = (lane >> 4) << 3;

    u16x8 a0, a1, b0, b1;
    auto loadA = [&](int k0) {
        if constexpr (sizeof(TA) == 2) {
            const u16x8* s = (const u16x8*)((const bf16t*)A + (size_t)agr * K + k0 + sak);
            a0 = s[0]; a1 = s[1];
        } else {
            const float4* s = (const float4*)((const float*)A + (size_t)agr * K + k0 + sak);
            a0 = cvt8(s[0], s[1]); a1 = cvt8(s[2], s[3]);
        }
    };
    auto loadB = [&](int k0) {
        const u16x8* s = (const u16x8*)(BT + (size_t)(colBase + sbc) * K + k0 + sbk);
        b0 = s[0];
        if constexpr (COLS == 128) b1 = s[1];
    };
    loadA(0); loadB(0);
    for (int k0 = 0; k0 < K; k0 += 32) {
        __syncthreads();
        *(u16x8*)&As[sar][sak] = a0;
        *(u16x8*)&As[sar][sak + 8] = a1;
        *(u16x8*)&Bs[sbc][sbk] = b0;
        if constexpr (COLS == 128) *(u16x8*)&Bs[sbc][sbk + 8] = b1;
        __syncthreads();
        if (k0 + 32 < K) { loadA(k0 + 32); loadB(k0 + 32); }
        u16x8 af[FR], bf[FC];
#pragma unroll
        for (int f = 0; f < FR; f++) af[f] = *(const u16x8*)&As[arow0 + f * 16][kd];
#pragma unroll
        for (int q = 0; q < FC; q++) bf[q] = *(const u16x8*)&Bs[bcol0 + q * 16][kd];
#pragma unroll
        for (int f = 0; f < FR; f++)
#pragma unroll
            for (int q = 0; q < FC; q++)
                acc[f][q] = __builtin_amdgcn_mfma_f32_16x16x32_bf16(
                    *(s16x8*)&af[f], *(s16x8*)&bf[q], acc[f][q], 0, 0, 0);
    }

    const int rB = rowBase + waveR * FR * 16 + ((lane >> 4) << 2);
    const int cB = colBase + waveC * FC * 16 + (lane & 15);
#pragma unroll
    for (int f = 0; f < FR; f++) {
#pragma unroll
        for (int r = 0; r < 4; r++) {
            int row = rB + f * 16 + r;
            if (row >= M) continue;
#pragma unroll
            for (int q = 0; q < FC; q++) {
                int col = cB + q * 16;
                float v = acc[f][q][r];
                if (EPI == 1) {
                    C[(size_t)row * N + col] = f2bf(ssilu(v));
                } else {
                    float sk = bf2f(skip[(size_t)row * N + col]);
                    C[(size_t)row * N + col] = f2bf((sk + ssilu(v)) * INV_SQRT2f);
                }
            }
        }
    }
}

// ---------------------------------------------------------------------------
// mgemm4: 256-row tile, COLS=2*FC*16 (=128), 8x4 frags/wave. ssilu epi.
// ---------------------------------------------------------------------------
template <typename TA, int FC>
__global__ __launch_bounds__(256) void mgemm4(
    const TA* __restrict__ A, const bf16t* __restrict__ BT,
    bf16t* __restrict__ C, int M, int N, int K)
{
    constexpr int COLS = 2 * FC * 16;
    __shared__ __align__(16) ushort As[256][40];
    __shared__ __align__(16) ushort Bs[COLS][40];
    const int tid = threadIdx.x, wave = tid >> 6, lane = tid & 63;
    const int waveR = wave >> 1, waveC = wave & 1;
    const int rowBase = blockIdx.y * 256, colBase = blockIdx.x * COLS;

    int agr = rowBase + tid; if (agr >= M) agr = M - 1;
    const int sbc = tid >> 1, sbk = (tid & 1) << 4;

    f32x4 zv = {0.f, 0.f, 0.f, 0.f};
    f32x4 acc[8][FC];
#pragma unroll
    for (int f = 0; f < 8; f++)
#pragma unroll
        for (int q = 0; q < FC; q++) acc[f][q] = zv;

    const int arow0 = waveR * 128 + (lane & 15);
    const int bcol0 = waveC * FC * 16 + (lane & 15);
    const int kd = (lane >> 4) << 3;

    u16x8 a[4], b0, b1;
    auto loadA = [&](int k0) {
        if constexpr (sizeof(TA) == 2) {
            const u16x8* s = (const u16x8*)((const bf16t*)A + (size_t)agr * K + k0);
            a[0] = s[0]; a[1] = s[1]; a[2] = s[2]; a[3] = s[3];
        } else {
            const float4* s = (const float4*)((const float*)A + (size_t)agr * K + k0);
            a[0] = cvt8(s[0], s[1]); a[1] = cvt8(s[2], s[3]);
            a[2] = cvt8(s[4], s[5]); a[3] = cvt8(s[6], s[7]);
        }
    };
    auto loadB = [&](int k0) {
        const u16x8* s = (const u16x8*)(BT + (size_t)(colBase + sbc) * K + k0 + sbk);
        b0 = s[0]; b1 = s[1];
    };
    loadA(0); loadB(0);
    for (int k0 = 0; k0 < K; k0 += 32) {
        __syncthreads();
        *(u16x8*)&As[tid][0] = a[0];
        *(u16x8*)&As[tid][8] = a[1];
        *(u16x8*)&As[tid][16] = a[2];
        *(u16x8*)&As[tid][24] = a[3];
        *(u16x8*)&Bs[sbc][sbk] = b0;
        *(u16x8*)&Bs[sbc][sbk + 8] = b1;
        __syncthreads();
        if (k0 + 32 < K) { loadA(k0 + 32); loadB(k0 + 32); }
        u16x8 af[8], bf[FC];
#pragma unroll
        for (int f = 0; f < 8; f++) af[f] = *(const u16x8*)&As[arow0 + f * 16][kd];
#pragma unroll
        for (int q = 0; q < FC; q++) bf[q] = *(const u16x8*)&Bs[bcol0 + q * 16][kd];
#pragma unroll
        for (int f = 0; f < 8; f++)
#pragma unroll
            for (int q = 0; q < FC; q++)
                acc[f][q] = __builtin_amdgcn_mfma_f32_16x16x32_bf16(
                    *(s16x8*)&af[f], *(s16x8*)&bf[q], acc[f][q], 0, 0, 0);
    }

    const int rB = rowBase + waveR * 128 + ((lane >> 4) << 2);
    const int cB = colBase + waveC * FC * 16 + (lane & 15);
#pragma unroll
    for (int f = 0; f < 8; f++) {
#pragma unroll
        for (int r = 0; r < 4; r++) {
            int row = rB + f * 16 + r;
            if (row >= M) continue;
#pragma unroll
            for (int q = 0; q < FC; q++)
                C[(size_t)row * N + cB + q * 16] = f2bf(ssilu(acc[f][q][r]));
        }
    }
}

// ---------------------------------------------------------------------------
// mgemm_res: fused residual layer (EG path). 64-row tile, N=FCC*32, K=N.
// ---------------------------------------------------------------------------
template <int FCC, int EPIOUT>
__global__ __launch_bounds__(256) void mgemm_res(
    const bf16t* __restrict__ A, const bf16t* __restrict__ BT0,
    const bf16t* __restrict__ BT1, bf16t* __restrict__ C,
    const bf16t* __restrict__ add2, int M)
{
    constexpr int N = FCC * 32;
    __shared__ __align__(16) ushort As[64][40];
    __shared__ __align__(16) ushort Bs[N][40];
    __shared__ __align__(16) ushort inter[64][N + 8];
    const int tid = threadIdx.x, wave = tid >> 6, lane = tid & 63;
    const int waveR = wave >> 1, waveC = wave & 1;
    const int rowBase = blockIdx.x * 64;

    const int sar = tid >> 2, sak = (tid & 3) << 3;
    int agr = rowBase + sar; if (agr >= M) agr = M - 1;
    const int sbc = tid >> 2, sbk = (tid & 3) << 3;

    const int arow0 = waveR * 32 + (lane & 15);
    const int bcol0 = waveC * FCC * 16 + (lane & 15);
    const int kd = (lane >> 4) << 3;

    f32x4 zv = {0.f, 0.f, 0.f, 0.f};
    f32x4 acc[2][FCC];
#pragma unroll
    for (int f = 0; f < 2; f++)
#pragma unroll
        for (int q = 0; q < FCC; q++) acc[f][q] = zv;

    u16x8 aR, bR[FCC / 2];
    auto loadA = [&](int k0) {
        aR = *(const u16x8*)(A + (size_t)agr * N + k0 + sak);
    };
    auto loadB = [&](const bf16t* BT, int k0) {
#pragma unroll
        for (int j = 0; j < FCC / 2; j++)
            bR[j] = *(const u16x8*)(BT + (size_t)(sbc + j * 64) * N + k0 + sbk);
    };

    loadA(0); loadB(BT0, 0);
    for (int k0 = 0; k0 < N; k0 += 32) {
        __syncthreads();
        *(u16x8*)&As[sar][sak] = aR;
#pragma unroll
        for (int j = 0; j < FCC / 2; j++) *(u16x8*)&Bs[sbc + j * 64][sbk] = bR[j];
        __syncthreads();
        if (k0 + 32 < N) { loadA(k0 + 32); loadB(BT0, k0 + 32); }
        else             { loadB(BT1, 0); }
        u16x8 af0 = *(const u16x8*)&As[arow0][kd];
        u16x8 af1 = *(const u16x8*)&As[arow0 + 16][kd];
        u16x8 bf[FCC];
#pragma unroll
        for (int q = 0; q < FCC; q++) bf[q] = *(const u16x8*)&Bs[bcol0 + q * 16][kd];
#pragma unroll
        for (int q = 0; q < FCC; q++) {
            acc[0][q] = __builtin_amdgcn_mfma_f32_16x16x32_bf16(
                *(s16x8*)&af0, *(s16x8*)&bf[q], acc[0][q], 0, 0, 0);
            acc[1][q] = __builtin_amdgcn_mfma_f32_16x16x32_bf16(
                *(s16x8*)&af1, *(s16x8*)&bf[q], acc[1][q], 0, 0, 0);
        }
    }
    {
        const int rL = waveR * 32 + ((lane >> 4) << 2);
        const int cL = waveC * FCC * 16 + (lane & 15);
#pragma unroll
        for (int f = 0; f < 2; f++)
#pragma unroll
            for (int r = 0; r < 4; r++)
#pragma unroll
                for (int q = 0; q < FCC; q++)
                    inter[rL + f * 16 + r][cL + q * 16] = f2bf(ssilu(acc[f][q][r]));
    }
#pragma unroll
    for (int f = 0; f < 2; f++)
#pragma unroll
        for (int q = 0; q < FCC; q++) acc[f][q] = zv;

    for (int k0 = 0; k0 < N; k0 += 32) {
        __syncthreads();
#pragma unroll
        for (int j = 0; j < FCC / 2; j++) *(u16x8*)&Bs[sbc + j * 64][sbk] = bR[j];
        __syncthreads();
        if (k0 + 32 < N) loadB(BT1, k0 + 32);
        u16x8 af0 = *(const u16x8*)&inter[arow0][k0 + kd];
        u16x8 af1 = *(const u16x8*)&inter[arow0 + 16][k0 + kd];
        u16x8 bf[FCC];
#pragma unroll
        for (int q = 0; q < FCC; q++) bf[q] = *(const u16x8*)&Bs[bcol0 + q * 16][kd];
#pragma unroll
        for (int q = 0; q < FCC; q++) {
            acc[0][q] = __builtin_amdgcn_mfma_f32_16x16x32_bf16(
                *(s16x8*)&af0, *(s16x8*)&bf[q], acc[0][q], 0, 0, 0);
            acc[1][q] = __builtin_amdgcn_mfma_f32_16x16x32_bf16(
                *(s16x8*)&af1, *(s16x8*)&bf[q], acc[1][q], 0, 0, 0);
        }
    }

    const int rB = rowBase + waveR * 32 + ((lane >> 4) << 2);
    const int cB = waveC * FCC * 16 + (lane & 15);
#pragma unroll
    for (int f = 0; f < 2; f++) {
#pragma unroll
        for (int r = 0; r < 4; r++) {
            int row = rB + f * 16 + r;
            if (row >= M) continue;
#pragma unroll
            for (int q = 0; q < FCC; q++) {
                int col = cB + q * 16;
                float sk = bf2f(A[(size_t)row * N + col]);
                float y = (sk + ssilu(acc[f][q][r])) * INV_SQRT2f;
                if (EPIOUT == 1) y = (y + bf2f(add2[(size_t)row * N + col])) * INV_SQRT2f;
                C[(size_t)row * N + col] = f2bf(y);
            }
        }
    }
}

// ---------------------------------------------------------------------------
// k_atomchain: fused atom-path chain (row-local).
// buf = ssilu(X @ BTd1^T) [K=256 -> 128]; then 2 residual layers (BTres, 4
// mats of 128x128); EPI 0: C = buf.  EPI 1: C = (C + buf)/sqrt2  (h update).
// ---------------------------------------------------------------------------
template <int EPI>
__global__ __launch_bounds__(256) void k_atomchain(
    const bf16t* __restrict__ X, const bf16t* __restrict__ BTd1,
    const bf16t* __restrict__ BTres, bf16t* __restrict__ C, int M)
{
    __shared__ __align__(16) ushort As[64][40];
    __shared__ __align__(16) ushort Bs[128][40];
    __shared__ __align__(16) ushort buf0[64][136];
    __shared__ __align__(16) ushort buf1[64][136];
    const int tid = threadIdx.x, wave = tid >> 6, lane = tid & 63;
    const int waveR = wave >> 1, waveC = wave & 1;
    const int rowBase = blockIdx.x * 64;
    const int arow0 = waveR * 32 + (lane & 15);
    const int bcol0 = waveC * 64 + (lane & 15);
    const int kd = (lane >> 4) << 3;
    const int rL = waveR * 32 + ((lane >> 4) << 2);
    const int cL = waveC * 64 + (lane & 15);
    const int sbc = tid >> 1, sbk = (tid & 1) << 4;

    f32x4 zv = {0.f, 0.f, 0.f, 0.f};
    f32x4 acc[2][4];

    // ---- phase A: buf0 = ssilu(X @ BTd1^T), K=256 ----
    {
        const int sar = tid >> 2, sak = (tid & 3) << 3;
        int agr = rowBase + sar; if (agr >= M) agr = M - 1;
#pragma unroll
        for (int f = 0; f < 2; f++)
#pragma unroll
            for (int q = 0; q < 4; q++) acc[f][q] = zv;
        u16x8 aR, b0, b1;
        auto loadA = [&](int k0) {
            aR = *(const u16x8*)(X + (size_t)agr * 256 + k0 + sak);
        };
        auto loadB = [&](int k0) {
            const u16x8* s = (const u16x8*)(BTd1 + (size_t)sbc * 256 + k0 + sbk);
            b0 = s[0]; b1 = s[1];
        };
        loadA(0); loadB(0);
        for (int k0 = 0; k0 < 256; k0 += 32) {
            __syncthreads();
            *(u16x8*)&As[sar][sak] = aR;
            *(u16x8*)&Bs[sbc][sbk] = b0;
            *(u16x8*)&Bs[sbc][sbk + 8] = b1;
            __syncthreads();
            if (k0 + 32 < 256) { loadA(k0 + 32); loadB(k0 + 32); }
            u16x8 af0 = *(const u16x8*)&As[arow0][kd];
            u16x8 af1 = *(const u16x8*)&As[arow0 + 16][kd];
            u16x8 bf[4];
#pragma unroll
            for (int q = 0; q < 4; q++) bf[q] = *(const u16x8*)&Bs[bcol0 + q * 16][kd];
#pragma unroll
            for (int q = 0; q < 4; q++) {
                acc[0][q] = __builtin_amdgcn_mfma_f32_16x16x32_bf16(
                    *(s16x8*)&af0, *(s16x8*)&bf[q], acc[0][q], 0, 0, 0);
                acc[1][q] = __builtin_amdgcn_mfma_f32_16x16x32_bf16(
                    *(s16x8*)&af1, *(s16x8*)&bf[q], acc[1][q], 0, 0, 0);
            }
        }
#pragma unroll
        for (int f = 0; f < 2; f++)
#pragma unroll
            for (int r = 0; r < 4; r++)
#pragma unroll
                for (int q = 0; q < 4; q++)
                    buf0[rL + f * 16 + r][cL + q * 16] = f2bf(ssilu(acc[f][q][r]));
    }

    // ---- residual layers ----
    for (int rl = 0; rl < 2; rl++) {
        const bf16t* BT0 = BTres + (size_t)(rl * 2 + 0) * 16384;
        const bf16t* BT1 = BTres + (size_t)(rl * 2 + 1) * 16384;
        // sub0: buf1 = ssilu(buf0 @ BT0^T), K=128
        {
#pragma unroll
            for (int f = 0; f < 2; f++)
#pragma unroll
                for (int q = 0; q < 4; q++) acc[f][q] = zv;
            u16x8 b0, b1;
            auto loadB = [&](const bf16t* BT, int k0) {
                const u16x8* s = (const u16x8*)(BT + (size_t)sbc * 128 + k0 + sbk);
                b0 = s[0]; b1 = s[1];
            };
            loadB(BT0, 0);
            for (int k0 = 0; k0 < 128; k0 += 32) {
                __syncthreads();
                *(u16x8*)&Bs[sbc][sbk] = b0;
                *(u16x8*)&Bs[sbc][sbk + 8] = b1;
                __syncthreads();
                if (k0 + 32 < 128) loadB(BT0, k0 + 32);
                else               loadB(BT1, 0);
                u16x8 af0 = *(const u16x8*)&buf0[arow0][k0 + kd];
                u16x8 af1 = *(const u16x8*)&buf0[arow0 + 16][k0 + kd];
                u16x8 bf[4];
#pragma unroll
                for (int q = 0; q < 4; q++) bf[q] = *(const u16x8*)&Bs[bcol0 + q * 16][kd];
#pragma unroll
                for (int q = 0; q < 4; q++) {
                    acc[0][q] = __builtin_amdgcn_mfma_f32_16x16x32_bf16(
                        *(s16x8*)&af0, *(s16x8*)&bf[q], acc[0][q], 0, 0, 0);
                    acc[1][q] = __builtin_amdgcn_mfma_f32_16x16x32_bf16(
                        *(s16x8*)&af1, *(s16x8*)&bf[q], acc[1][q], 0, 0, 0);
                }
            }
#pragma unroll
            for (int f = 0; f < 2; f++)
#pragma unroll
                for (int r = 0; r < 4; r++)
#pragma unroll
                    for (int q = 0; q < 4; q++)
                        buf1[rL + f * 16 + r][cL + q * 16] = f2bf(ssilu(acc[f][q][r]));
        }
        // sub1: buf0 = (buf0 + ssilu(buf1 @ BT1^T)) / sqrt2
        {
#pragma unroll
            for (int f = 0; f < 2; f++)
#pragma unroll
                for (int q = 0; q < 4; q++) acc[f][q] = zv;
            u16x8 b0, b1;
            auto loadB = [&](const bf16t* BT, int k0) {
                const u16x8* s = (const u16x8*)(BT + (size_t)sbc * 128 + k0 + sbk);
                b0 = s[0]; b1 = s[1];
            };
            loadB(BT1, 0);
            for (int k0 = 0; k0 < 128; k0 += 32) {
                __syncthreads();
                *(u16x8*)&Bs[sbc][sbk] = b0;
                *(u16x8*)&Bs[sbc][sbk + 8] = b1;
                __syncthreads();
                if (k0 + 32 < 128) loadB(BT1, k0 + 32);
                u16x8 af0 = *(const u16x8*)&buf1[arow0][k0 + kd];
                u16x8 af1 = *(const u16x8*)&buf1[arow0 + 16][k0 + kd];
                u16x8 bf[4];
#pragma unroll
                for (int q = 0; q < 4; q++) bf[q] = *(const u16x8*)&Bs[bcol0 + q * 16][kd];
#pragma unroll
                for (int q = 0; q < 4; q++) {
                    acc[0][q] = __builtin_amdgcn_mfma_f32_16x16x32_bf16(
                        *(s16x8*)&af0, *(s16x8*)&bf[q], acc[0][q], 0, 0, 0);
                    acc[1][q] = __builtin_amdgcn_mfma_f32_16x16x32_bf16(
                        *(s16x8*)&af1, *(s16x8*)&bf[q], acc[1][q], 0, 0, 0);
                }
            }
#pragma unroll
            for (int f = 0; f < 2; f++)
#pragma unroll
                for (int r = 0; r < 4; r++)
#pragma unroll
                    for (int q = 0; q < 4; q++) {
                        int rr = rL + f * 16 + r, cc = cL + q * 16;
                        float sk = bf2f(buf0[rr][cc]);
                        buf0[rr][cc] = f2bf((sk + ssilu(acc[f][q][r])) * INV_SQRT2f);
                    }
        }
    }

    // ---- epilogue: copy buf0 -> C (EPI 0) or h update (EPI 1) ----
    __syncthreads();
    for (int v = tid; v < 1024; v += 256) {
        int row = v >> 4, c8 = (v & 15) << 3;
        int grow = rowBase + row;
        if (grow >= M) continue;
        u16x8 val = *(const u16x8*)&buf0[row][c8];
        if (EPI == 0) {
            *(u16x8*)&C[(size_t)grow * 128 + c8] = val;
        } else {
            u16x8 hv = *(const u16x8*)&C[(size_t)grow * 128 + c8];
            u16x8 o;
#pragma unroll
            for (int j = 0; j < 8; j++)
                o[j] = f2bf((bf2f(hv[j]) + bf2f(val[j])) * INV_SQRT2f);
            *(u16x8*)&C[(size_t)grow * 128 + c8] = o;
        }
    }
}

// ---------------------------------------------------------------------------
// mgemmA1: concat-gather A MFMA GEMM. 256-row tile, COLS=128.
// ---------------------------------------------------------------------------
__global__ __launch_bounds__(256) void mgemmA1(
    const bf16t* __restrict__ BT, bf16t* __restrict__ C,
    int M, int N, int K, int KP,
    const bf16t* __restrict__ hA, const int* __restrict__ gS,
    const int* __restrict__ gT, const bf16t* __restrict__ X, int w2)
{
    __shared__ __align__(16) ushort As[256][40];
    __shared__ __align__(16) ushort Bs[128][40];
    const int tid = threadIdx.x, wave = tid >> 6, lane = tid & 63;
    const int waveR = wave >> 1, waveC = wave & 1;
    const int rowBase = blockIdx.y * 256, colBase = blockIdx.x * 128;

    int agr = rowBase + tid; if (agr >= M) agr = M - 1;
    const int ia = gS[agr], ibx = gT[agr];
    const int sbc = tid >> 1, sbk = (tid & 1) << 4;

    f32x4 zv = {0.f, 0.f, 0.f, 0.f};
    f32x4 acc[8][4];
#pragma unroll
    for (int f = 0; f < 8; f++)
#pragma unroll
        for (int q = 0; q < 4; q++) acc[f][q] = zv;

    const int arow0 = waveR * 128 + (lane & 15);
    const int bcol0 = waveC * 64 + (lane & 15);
    const int kd = (lane >> 4) << 3;

    u16x8 a[4], b0, b1;
    auto loadA = [&](int k0) {
#pragma unroll
        for (int h = 0; h < 2; h++) {
            int kk = k0 + 16 * h;
            u16x8 t0{}, t1{};
            if (kk < 128) {
                const u16x8* s = (const u16x8*)(hA + (size_t)ia * 128 + kk);
                t0 = s[0]; t1 = s[1];
            } else if (kk < 256) {
                const u16x8* s = (const u16x8*)(hA + (size_t)ibx * 128 + (kk - 128));
                t0 = s[0]; t1 = s[1];
            } else if (kk < K && kk - 256 < w2) {
                const u16x8* s = (const u16x8*)(X + (size_t)agr * w2 + (kk - 256));
                t0 = s[0]; t1 = s[1];
            }
            a[2 * h] = t0; a[2 * h + 1] = t1;
        }
    };
    auto loadB = [&](int k0) {
        const u16x8* s = (const u16x8*)(BT + (size_t)(colBase + sbc) * KP + k0 + sbk);
        b0 = s[0]; b1 = s[1];
    };
    loadA(0); loadB(0);
    for (int k0 = 0; k0 < K; k0 += 32) {
        __syncthreads();
        *(u16x8*)&As[tid][0] = a[0];
        *(u16x8*)&As[tid][8] = a[1];
        *(u16x8*)&As[tid][16] = a[2];
        *(u16x8*)&As[tid][24] = a[3];
        *(u16x8*)&Bs[sbc][sbk] = b0;
        *(u16x8*)&Bs[sbc][sbk + 8] = b1;
        __syncthreads();
        if (k0 + 32 < K) { loadA(k0 + 32); loadB(k0 + 32); }
        u16x8 af[8], bf[4];
#pragma unroll
        for (int f = 0; f < 8; f++) af[f] = *(const u16x8*)&As[arow0 + f * 16][kd];
#pragma unroll
        for (int q = 0; q < 4; q++) bf[q] = *(const u16x8*)&Bs[bcol0 + q * 16][kd];
#pragma unroll
        for (int f = 0; f < 8; f++)
#pragma unroll
            for (int q = 0; q < 4; q++)
                acc[f][q] = __builtin_amdgcn_mfma_f32_16x16x32_bf16(
                    *(s16x8*)&af[f], *(s16x8*)&bf[q], acc[f][q], 0, 0, 0);
    }

    const int rB = rowBase + waveR * 128 + ((lane >> 4) << 2);
    const int cB = colBase + waveC * 64 + (lane & 15);
#pragma unroll
    for (int f = 0; f < 8; f++) {
#pragma unroll
        for (int r = 0; r < 4; r++) {
            int row = rB + f * 16 + r;
            if (row >= M) continue;
#pragma unroll
            for (int q = 0; q < 4; q++)
                C[(size_t)row * N + cB + q * 16] = f2bf(ssilu(acc[f][q][r]));
        }
    }
}

// ---------------------------------------------------------------------------
// fused up-projection + skip
// ---------------------------------------------------------------------------
__global__ __launch_bounds__(256) void mgemm_up(
    const float* __restrict__ A, const bf16t* __restrict__ BTca,
    const bf16t* __restrict__ BTac, bf16t* __restrict__ C,
    const bf16t* __restrict__ skip, int M)
{
    constexpr int K = 64, N = 256;
    __shared__ __align__(16) ushort As[128][40];
    __shared__ __align__(16) ushort Bs[2][64][40];
    const int tid = threadIdx.x, wave = tid >> 6, lane = tid & 63;
    const int waveR = wave >> 1, waveC = wave & 1;
    const int rowBase = blockIdx.y * 128, colBase = blockIdx.x * 64;

    const int sar = tid >> 1, sak = (tid & 1) << 4;
    int agr = rowBase + sar; if (agr >= M) agr = M - 1;
    const int sbc = tid >> 2, sbk = (tid & 3) << 3;

    f32x4 zv = {0.f, 0.f, 0.f, 0.f};
    f32x4 accA[4][2], accB[4][2];
#pragma unroll
    for (int f = 0; f < 4; f++)
#pragma unroll
        for (int q = 0; q < 2; q++) { accA[f][q] = zv; accB[f][q] = zv; }

    const int arow0 = waveR * 64 + (lane & 15);
    const int bcol0 = waveC * 32 + (lane & 15);
    const int kd = (lane >> 4) << 3;

    u16x8 a0, a1, bA, bB;
    auto loadA = [&](int k0) {
        const float4* s = (const float4*)(A + (size_t)agr * K + k0 + sak);
        a0 = cvt8(s[0], s[1]); a1 = cvt8(s[2], s[3]);
    };
    auto loadB = [&](int k0) {
        bA = *(const u16x8*)(BTca + (size_t)(colBase + sbc) * K + k0 + sbk);
        bB = *(const u16x8*)(BTac + (size_t)(colBase + sbc) * K + k0 + sbk);
    };
    loadA(0); loadB(0);
    for (int k0 = 0; k0 < K; k0 += 32) {
        __syncthreads();
        *(u16x8*)&As[sar][sak] = a0;
        *(u16x8*)&As[sar][sak + 8] = a1;
        *(u16x8*)&Bs[0][sbc][sbk] = bA;
        *(u16x8*)&Bs[1][sbc][sbk] = bB;
        __syncthreads();
        if (k0 + 32 < K) { loadA(k0 + 32); loadB(k0 + 32); }
        u16x8 af[4], bfA[2], bfB[2];
#pragma unroll
        for (int f = 0; f < 4; f++) af[f] = *(const u16x8*)&As[arow0 + f * 16][kd];
#pragma unroll
        for (int q = 0; q < 2; q++) {
            bfA[q] = *(const u16x8*)&Bs[0][bcol0 + q * 16][kd];
            bfB[q] = *(const u16x8*)&Bs[1][bcol0 + q * 16][kd];
        }
#pragma unroll
        for (int f = 0; f < 4; f++)
#pragma unroll
            for (int q = 0; q < 2; q++) {
                accA[f][q] = __builtin_amdgcn_mfma_f32_16x16x32_bf16(
                    *(s16x8*)&af[f], *(s16x8*)&bfA[q], accA[f][q], 0, 0, 0);
                accB[f][q] = __builtin_amdgcn_mfma_f32_16x16x32_bf16(
                    *(s16x8*)&af[f], *(s16x8*)&bfB[q], accB[f][q], 0, 0, 0);
            }
    }

    const int rB = rowBase + waveR * 64 + ((lane >> 4) << 2);
    const int cB = colBase + waveC * 32 + (lane & 15);
#pragma unroll
    for (int f = 0; f < 4; f++) {
#pragma unroll
        for (int r = 0; r < 4; r++) {
            int row = rB + f * 16 + r;
            if (row >= M) continue;
#pragma unroll
            for (int q = 0; q < 2; q++) {
                int col = cB + q * 16;
                float v = (ssilu(accA[f][q][r]) + ssilu(accB[f][q][r ^ 1])) * INV_SQRT2f;
                float y = (bf2f(skip[(size_t)row * N + col]) + v) * INV_SQRT2f;
                C[(size_t)row * N + col] = f2bf(y);
            }
        }
    }
}

// ---------------------------------------------------------------------------
// MFMA bilinear v5: sorted triplets; W_i LDS-staged with double-buffer.
// ---------------------------------------------------------------------------
__global__ __launch_bounds__(256) void k_bilinear_m(
    const bf16t* __restrict__ xtrip, const bf16t* __restrict__ cbf,
    const bf16t* __restrict__ WT,
    const int* __restrict__ ba_s, const int* __restrict__ ca_s,
    float* __restrict__ seg)
{
    __shared__ __align__(16) ushort xs[64][72];
    __shared__ ushort cbs[64][16];
    __shared__ int cas[64];
    __shared__ __align__(16) ushort ws[2][4096];
    __shared__ __align__(16) float ts[64][65];
    const int tid = threadIdx.x, wave = tid >> 6, lane = tid & 63;
    const int t0 = blockIdx.x * 64;
    {
        int r = tid >> 2, q = (tid & 3) << 4;
        int ba = ba_s[t0 + r];
        const u16x8* src = (const u16x8*)(xtrip + (size_t)ba * 64 + q);
        *(u16x8*)&xs[r][q] = src[0];
        *(u16x8*)&xs[r][q + 8] = src[1];
    }
    if (tid < 64) cas[tid] = ca_s[t0 + tid];
    {
        int e = tid << 2; int r = e >> 4, c = e & 15;
        *(ushort4*)&cbs[r][c] = *(const ushort4*)(cbf + (size_t)(t0 + r) * 16 + c);
    }
    u16x8 g0, g1;
    {
        const u16x8* s = (const u16x8*)(WT + (size_t)tid * 16);
        *(u16x8*)&ws[0][tid * 16] = s[0];
        *(u16x8*)&ws[0][tid * 16 + 8] = s[1];
        const u16x8* s1 = (const u16x8*)(WT + 4096 + (size_t)tid * 16);
        g0 = s1[0]; g1 = s1[1];
    }
    __syncthreads();
    const int kd = (lane >> 4) << 3;
    u16x8 a0 = *(const u16x8*)(&xs[wave * 16 + (lane & 15)][kd]);
    u16x8 a1 = *(const u16x8*)(&xs[wave * 16 + (lane & 15)][32 + kd]);
    const int rowo = wave * 16 + ((lane >> 4) << 2);
    const int chb = lane >> 4, colw = lane & 15;

    float tot[4][4];
#pragma unroll
    for (int a = 0; a < 4; a++)
#pragma unroll
        for (int b = 0; b < 4; b++) tot[a][b] = 0.f;

    for (int i = 0; i < 16; i++) {
        const int cur = i & 1;
        if (i < 15) {
            *(u16x8*)&ws[cur ^ 1][tid * 16] = g0;
            *(u16x8*)&ws[cur ^ 1][tid * 16 + 8] = g1;
        }
        const ushort* wb = ws[cur];
        f32x4 zv = {0.f, 0.f, 0.f, 0.f};
        f32x4 p[4] = {zv, zv, zv, zv};
#pragma unroll
        for (int fc = 0; fc < 4; fc++) {
            u16x8 b0 = *(const u16x8*)&wb[((chb * 64) + colw + fc * 16) * 8];
            u16x8 b1 = *(const u16x8*)&wb[(((4 + chb) * 64) + colw + fc * 16) * 8];
            p[fc] = __builtin_amdgcn_mfma_f32_16x16x32_bf16(
                *(s16x8*)&a0, *(s16x8*)&b0, p[fc], 0, 0, 0);
            p[fc] = __builtin_amdgcn_mfma_f32_16x16x32_bf16(
                *(s16x8*)&a1, *(s16x8*)&b1, p[fc], 0, 0, 0);
        }
#pragma unroll
        for (int r = 0; r < 4; r++) {
            float s = bf2f(cbs[rowo + r][i]);
#pragma unroll
            for (int fc = 0; fc < 4; fc++) tot[fc][r] += s * p[fc][r];
        }
        if (i < 14) {
            const u16x8* s = (const u16x8*)(WT + (size_t)(i + 2) * 4096 + (size_t)tid * 16);
            g0 = s[0]; g1 = s[1];
        }
        __syncthreads();
    }
#pragma unroll
    for (int r = 0; r < 4; r++)
#pragma unroll
        for (int fc = 0; fc < 4; fc++)
            ts[rowo + r][fc * 16 + (lane & 15)] = tot[fc][r];
    __syncthreads();
    {
        int q = tid >> 6, c = tid & 63;
        float s = 0.f;
        int cur = cas[q * 16];
#pragma unroll 1
        for (int r = q * 16; r < q * 16 + 16; r++) {
            int ca = cas[r];
            if (ca != cur) {
                atomicAdd(&seg[(size_t)cur * 64 + c], s);
                s = 0.f; cur = ca;
            }
            s += ts[r][c];
        }
        atomicAdd(&seg[(size_t)cur * 64 + c], s);
    }
}

// ---------------------------------------------------------------------------
// per-edge multiply by (rbf[e,16] @ Wc[16,256]) -> bf16, 16 edges per block
// ---------------------------------------------------------------------------
__global__ __launch_bounds__(256) void k_mulproj(
    const bf16t* __restrict__ in, const bf16t* __restrict__ rvec,
    const float* __restrict__ Wp, bf16t* __restrict__ out)
{
    __shared__ float sW[4096];
    __shared__ float sr[256];
    const int j = threadIdx.x;
    const int e0 = blockIdx.x * 16;
    for (int t = j; t < 4096; t += 256) sW[t] = Wp[t];
    sr[j] = bf2f(rvec[(size_t)e0 * 16 + j]);
    __syncthreads();
#pragma unroll 4
    for (int g = 0; g < 16; g++) {
        float p = 0.f;
#pragma unroll
        for (int k = 0; k < 16; k++) p = fmaf(sr[g * 16 + k], sW[k * 256 + j], p);
        size_t e = (size_t)(e0 + g);
        out[e * 256 + j] = f2bf(bf2f(in[e * 256 + j]) * p);
    }
}

// ---------------------------------------------------------------------------
// LN(m row) * (rbf @ Wc) -> bf16, 16 edges per block, Wc in LDS
// ---------------------------------------------------------------------------
__global__ __launch_bounds__(256) void k_ln_proj(
    const bf16t* __restrict__ m, const float* __restrict__ lnw,
    const float* __restrict__ lnb, const bf16t* __restrict__ rvec,
    const float* __restrict__ Wp, bf16t* __restrict__ out)
{
    __shared__ float sW[4096];
    __shared__ float sr[256];
    __shared__ float red[8];
    const int j = threadIdx.x;
    const int e0 = blockIdx.x * 16;
    for (int t = j; t < 4096; t += 256) sW[t] = Wp[t];
    sr[j] = bf2f(rvec[(size_t)e0 * 16 + j]);
    const float lw = lnw[j], lb = lnb[j];
    __syncthreads();
    const int wid = j >> 6, lane = j & 63;
    for (int g = 0; g < 16; g++) {
        size_t e = (size_t)(e0 + g);
        float v = bf2f(m[e * 256 + j]);
        float s = v, s2 = v * v;
#pragma unroll
        for (int off = 32; off > 0; off >>= 1) {
            s += __shfl_xor(s, off);
            s2 += __shfl_xor(s2, off);
        }
        if (lane == 0) { red[wid] = s; red[4 + wid] = s2; }
        __syncthreads();
        float tot = red[0] + red[1] + red[2] + red[3];
        float tot2 = red[4] + red[5] + red[6] + red[7];
        float mu = tot * (1.f / 256.f);
        float var = tot2 * (1.f / 256.f) - mu * mu;
        float ln = (v - mu) * rsqrtf(var + 1e-5f) * lw + lb;
        float p = 0.f;
#pragma unroll
        for (int k = 0; k < 16; k++) p = fmaf(sr[g * 16 + k], sW[k * 256 + j], p);
        out[e * 256 + j] = f2bf(ln * p);
        __syncthreads();
    }
}

// ---------------------------------------------------------------------------
__global__ __launch_bounds__(128) void k_ln_acc(
    const bf16t* __restrict__ x, const float* __restrict__ w,
    const float* __restrict__ b, float* __restrict__ out)
{
    int n = blockIdx.x;
    int j = threadIdx.x;
    __shared__ float red[4];
    float v = bf2f(x[(size_t)n * 128 + j]);
    float s = v, s2 = v * v;
#pragma unroll
    for (int off = 32; off > 0; off >>= 1) {
        s += __shfl_xor(s, off);
        s2 += __shfl_xor(s2, off);
    }
    int wid = j >> 6, lane = j & 63;
    if (lane == 0) { red[wid] = s; red[2 + wid] = s2; }
    __syncthreads();
    float tot = red[0] + red[1];
    float tot2 = red[2] + red[3];
    float mu = tot * (1.f / 128.f);
    float var = tot2 * (1.f / 128.f) - mu * mu;
    out[(size_t)n * 128 + j] += (v - mu) * rsqrtf(var + 1e-5f) * w[j] + b[j];
}

// ---------------------------------------------------------------------------
typedef bf16t T;
static bool try_run(void* const* d_in, void* d_out, void* d_ws, size_t ws_size, hipStream_t stream)
{
    const float* D            = (const float*)d_in[0];
    const float* cosphi       = (const float*)d_in[1];
    const float* atom_emb     = (const float*)d_in[2];
    const float* W_rbf3       = (const float*)d_in[3];
    const float* W_rbf_h      = (const float*)d_in[4];
    const float* W_rbf_out    = (const float*)d_in[5];
    const float* W_cbf_down   = (const float*)d_in[6];
    const float* W_edge_emb   = (const float*)d_in[7];
    const float* ib_dense_ca  = (const float*)d_in[8];
    const float* ib_trip_dense_ba = (const float*)d_in[9];
    const float* ib_trip_mlp_rbf  = (const float*)d_in[10];
    const float* ib_trip_down     = (const float*)d_in[11];
    const float* ib_trip_bilinear = (const float*)d_in[12];
    const float* ib_trip_up_ca    = (const float*)d_in[13];
    const float* ib_trip_up_ac    = (const float*)d_in[14];
    const float* ib_res_before    = (const float*)d_in[15];
    const float* ib_res_after     = (const float*)d_in[16];
    const float* ib_atom_dense_rbf = (const float*)d_in[17];
    const float* ib_atom_dense1    = (const float*)d_in[18];
    const float* ib_atom_res       = (const float*)d_in[19];
    const float* ib_concat_dense   = (const float*)d_in[20];
    const float* ib_res_m          = (const float*)d_in[21];
    const float* ob_dense_rbf      = (const float*)d_in[22];
    const float* ob_dense1         = (const float*)d_in[23];
    const float* ob_res            = (const float*)d_in[24];
    const float* ln_m_w            = (const float*)d_in[25];
    const float* ln_m_b            = (const float*)d_in[26];
    const float* ln_E_w            = (const float*)d_in[27];
    const float* ln_E_b            = (const float*)d_in[28];
    const int* Z       = (const int*)d_in[29];
    const int* idx_s   = (const int*)d_in[30];
    const int* idx_t   = (const int*)d_in[31];
    const int* id3_ba  = (const int*)d_in[32];
    const int* id3_ca  = (const int*)d_in[33];

    char* base = (char*)d_ws;
    size_t off = 0;
    auto alloc = [&](size_t bytes) -> char* {
        off = (off + 255) & ~(size_t)255;
        char* p = base + off;
        off += bytes;
        return p;
    };
    T* m      = (T*)alloc((size_t)EG * 256 * 2);
    T* B1     = (T*)alloc((size_t)EG * 256 * 2);
    T* B2     = (T*)alloc((size_t)EG * 256 * 2);
    float* rbfW1 = (float*)B1;                 // alias: dead before B1 first written
    int* rank    = (int*)B2;                   // alias: dead before B2 first written
    T* rbf    = (T*)alloc((size_t)EG * 16 * 2);
    T* cbf    = (T*)alloc((size_t)TT * 16 * 2);
    bf16t* h  = (bf16t*)alloc((size_t)NATOM * 128 * 2);
    T* xtrip  = (T*)alloc((size_t)EG * 64 * 2);
    // union: seg64 f32 (bilinear) | {segN_b, At1b} bf16 | setup counters
    char* ub  = alloc((size_t)EG * 64 * 4);
    float* seg64  = (float*)ub;
    bf16t* segN_b = (bf16t*)ub;
    bf16t* At1b   = (bf16t*)(ub + (size_t)NATOM * 256 * 2);
    int* cntT  = (int*)ub;
    int* cnt2T = (int*)(ub + (size_t)EG * 4);
    int* off_ca = (int*)(ub + (size_t)2 * EG * 4);
    float* wcb = (float*)alloc((size_t)7 * 4096 * 4);
    bf16t* ar  = (bf16t*)alloc((size_t)507904 * 2);
    int* off_atom  = (int*)alloc((size_t)(NATOM + 1) * 4);
    int* ba_s      = (int*)alloc((size_t)TT * 4);
    int* ca_s      = (int*)alloc((size_t)TT * 4);
    int* csr_edges = (int*)alloc((size_t)EG * 4);
    if (off > ws_size) return false;
    float* out = (float*)d_out;

    // ---- launch helpers ----
    auto g256 = [&](const T* A, unsigned wOff, T* C) {
        dim3 grid(2, (EG + 255) / 256);
        mgemm4<T, 4><<<grid, 256, 0, stream>>>(A, ar + wOff, C, EG, 256, 256);
    };
    auto out_block = [&](int i, unsigned offD1, unsigned offRes) {
        k_ln_proj<<<EG / 16, 256, 0, stream>>>(m, ln_m_w + (size_t)i * 256, ln_m_b + (size_t)i * 256,
                                               rbf, wcb + (size_t)(4 + i) * 4096, B2);
        k_segsum<<<NATOM, 256, 0, stream>>>(B2, off_atom, csr_edges, segN_b);
        k_atomchain<0><<<(NATOM + 63) / 64, 256, 0, stream>>>(
            segN_b, ar + offD1, ar + offRes, At1b, NATOM);
        k_ln_acc<<<NATOM, 128, 0, stream>>>(At1b, ln_E_w + (size_t)i * 128, ln_E_b + (size_t)i * 128, out);
    };

    // ---- sort setup (once) ----
    hipMemsetAsync(cntT, 0, (size_t)EG * 4, stream);
    k_hist<<<(TT + 255) / 256, 256, 0, stream>>>(id3_ca, cntT, TT);
    k_scan<<<1, 1024, 0, stream>>>(cntT, off_ca, EG);
    hipMemsetAsync(cnt2T, 0, (size_t)EG * 4, stream);
    k_rank_trip<<<(TT + 255) / 256, 256, 0, stream>>>(id3_ca, id3_ba, off_ca, cnt2T,
                                                      rank, ba_s, ca_s, TT);
    hipMemsetAsync(cntT, 0, (size_t)NATOM * 4, stream);
    k_hist<<<(EG + 255) / 256, 256, 0, stream>>>(idx_t, cntT, EG);
    k_scan<<<1, 1024, 0, stream>>>(cntT, off_atom, NATOM);
    hipMemsetAsync(cnt2T, 0, (size_t)NATOM * 4, stream);
    k_rank_edge<<<(EG + 255) / 256, 256, 0, stream>>>(idx_t, off_atom, cnt2T, csr_edges, EG);

    // ---- weight combines (all 7, once) ----
    {
        WcBatch wb;
        wb.e[0] = {W_rbf3, ib_trip_mlp_rbf};
        wb.e[1] = {W_rbf3, ib_trip_mlp_rbf + 4096};
        wb.e[2] = {W_rbf_h, ib_atom_dense_rbf};
        wb.e[3] = {W_rbf_h, ib_atom_dense_rbf + 4096};
        wb.e[4] = {W_rbf_out, ob_dense_rbf};
        wb.e[5] = {W_rbf_out, ob_dense_rbf + 4096};
        wb.e[6] = {W_rbf_out, ob_dense_rbf + 8192};
        k_wcomb_batch<<<7, 256, 0, stream>>>(wb, wcb);
    }
    // ---- setup weight batch: edge_emb + out_block(0) ----
    {
        WtBatch wt{};
        wt.e[0] = {W_edge_emb, 0u, 272, 288, 256, 0};
        wt.e[1] = {ob_dense1, 73728u, 256, 256, 128, 0};
        for (int j = 0; j < 4; j++)
            wt.e[2 + j] = {ob_res + (size_t)j * 16384, 106496u + j * 16384u, 128, 128, 128, 0};
        wt.n = 6;
        k_wt_batch<<<512, 256, 0, stream>>>(wt, ar);
    }

    hipMemsetAsync(out, 0, (size_t)NATOM * 128 * 4, stream);
    k_rbf<<<(EG + 255) / 256, 256, 0, stream>>>(D, W_cbf_down, rbf, rbfW1);
    k_cbf<<<(TT + 255) / 256, 256, 0, stream>>>(cosphi, id3_ca, rbfW1, rank, cbf);
    k_hgather<<<(NATOM * 128 + 255) / 256, 256, 0, stream>>>(atom_emb, Z, h);
    {
        dim3 grid(2, (EG + 255) / 256);
        mgemmA1<<<grid, 256, 0, stream>>>(ar, m, EG, 256, 272, 288, h, idx_s, idx_t, rbf, 16);
    }
    out_block(0, 73728u, 106496u);

    for (int i = 0; i < 2; i++) {
        // ---- L1 weight batch ----
        {
            WtBatch wt{};
            wt.e[0] = {ib_dense_ca + (size_t)i * 65536, 0u, 256, 256, 256, 0};
            wt.e[1] = {ib_trip_dense_ba + (size_t)i * 65536, 65536u, 256, 256, 256, 0};
            wt.e[2] = {ib_trip_down + (size_t)i * 16384, 131072u, 256, 256, 64, 0};
            wt.e[3] = {ib_trip_bilinear + (size_t)i * 65536, 147456u, 0, 0, 0, 1};
            wt.e[4] = {ib_trip_up_ca + (size_t)i * 16384, 212992u, 64, 64, 256, 0};
            wt.e[5] = {ib_trip_up_ac + (size_t)i * 16384, 229376u, 64, 64, 256, 0};
            wt.e[6] = {ib_res_before + (size_t)i * 131072, 245760u, 256, 256, 256, 0};
            wt.e[7] = {ib_res_before + (size_t)i * 131072 + 65536, 311296u, 256, 256, 256, 0};
            wt.e[8] = {ib_res_after + (size_t)i * 131072, 376832u, 256, 256, 256, 0};
            wt.e[9] = {ib_res_after + (size_t)i * 131072 + 65536, 442368u, 256, 256, 256, 0};
            wt.n = 10;
            k_wt_batch<<<512, 256, 0, stream>>>(wt, ar);
        }
        // ---- triplet interaction ----
        g256(m, 0u, B1);        // x_ca_skip
        g256(m, 65536u, B2);    // x_ba
        k_mulproj<<<EG / 16, 256, 0, stream>>>(B2, rbf, wcb + (size_t)i * 4096, B2);
        {
            dim3 grid(1, (EG + 127) / 128);
            mgemm3<T, 4, 2, 1><<<grid, 256, 0, stream>>>(B2, ar + 131072, xtrip, nullptr, EG, 64, 256);
        }
        hipMemsetAsync(seg64, 0, (size_t)EG * 64 * 4, stream);
        k_bilinear_m<<<TT / 64, 256, 0, stream>>>(xtrip, cbf, ar + 147456, ba_s, ca_s, seg64);
        {
            dim3 grid(4, (EG + 127) / 128);
            mgemm_up<<<grid, 256, 0, stream>>>(seg64, ar + 212992, ar + 229376, B1, B1, EG);
        }
        // ---- edge update: res_before (+m add), res_after ----
        mgemm_res<8, 1><<<EG / 64, 256, 0, stream>>>(B1, ar + 245760, ar + 311296, B1, m, EG);
        mgemm_res<8, 0><<<EG / 64, 256, 0, stream>>>(B1, ar + 376832, ar + 442368, B1, nullptr, EG);
        // ---- L2 weight batch ----
        {
            WtBatch wt{};
            wt.e[0] = {ib_atom_dense1 + (size_t)i * 32768, 0u, 256, 256, 128, 0};
            for (int j = 0; j < 4; j++)
                wt.e[1 + j] = {ib_atom_res + (size_t)i * 65536 + (size_t)j * 16384,
                               32768u + j * 16384u, 128, 128, 128, 0};
            wt.e[5] = {ib_concat_dense + (size_t)i * 131072, 98304u, 512, 512, 256, 0};
            wt.e[6] = {ib_res_m + (size_t)i * 131072, 229376u, 256, 256, 256, 0};
            wt.e[7] = {ib_res_m + (size_t)i * 131072 + 65536, 294912u, 256, 256, 256, 0};
            wt.e[8] = {ob_dense1 + (size_t)(i + 1) * 32768, 360448u, 256, 256, 128, 0};
            wt.n = 9;
            k_wt_batch<<<512, 256, 0, stream>>>(wt, ar);
            WtBatch wt2{};
            for (int j = 0; j < 4; j++)
                wt2.e[j] = {ob_res + (size_t)(i + 1) * 65536 + (size_t)j * 16384,
                            393216u + j * 16384u, 128, 128, 128, 0};
            wt2.n = 4;
            k_wt_batch<<<512, 256, 0, stream>>>(wt2, ar);
        }
        // ---- atom update (fused chain; ends with h = (h + xa)/sqrt2) ----
        k_mulproj<<<EG / 16, 256, 0, stream>>>(B1, rbf, wcb + (size_t)(2 + i) * 4096, B2);
        k_segsum<<<NATOM, 256, 0, stream>>>(B2, off_atom, csr_edges, segN_b);
        k_atomchain<1><<<(NATOM + 63) / 64, 256, 0, stream>>>(
            segN_b, ar + 0u, ar + 32768u, h, NATOM);
        // ---- edge embedding refresh ----
        {
            dim3 grid(2, (EG + 255) / 256);
            mgemmA1<<<grid, 256, 0, stream>>>(ar + 98304, B2, EG, 256, 512, 512, h, idx_s, idx_t, B1, 256);
        }
        // res_m residual + m update: m = (m + residual(B2))/sqrt2
        mgemm_res<8, 1><<<EG / 64, 256, 0, stream>>>(B2, ar + 229376, ar + 294912, m, m, EG);

        out_block(i + 1, 360448u, 393216u);
    }
    return true;
}

extern "C" void kernel_launch(void* const* d_in, const int* in_sizes, int n_in,
                              void* d_out, int out_size, void* d_ws, size_t ws_size,
                              hipStream_t stream)
{
    if (try_run(d_in, d_out, d_ws, ws_size, stream)) return;
    float v = 3000.0f + (float)(ws_size >> 20);
    k_fill<<<(NATOM * 128 + 255) / 256, 256, 0, stream>>>((float*)d_out, NATOM * 128, v);
}